// Round 8
// baseline (983.059 us; speedup 1.0000x reference)
//
#include <hip/hip_runtime.h>

#define BATCH 64
#define LHIST 12
#define NNODE 4096
#define CCH   3
#define FD    32
#define HD    64
#define OUTD  12
#define TIDN  288
#define DIWN  7
#define TDD   16
#define EMBD  10
#define MROWS 2048
#define KDIM  4096
#define MTOT  (BATCH * NNODE)

typedef __attribute__((ext_vector_type(8))) short bf16x8;
typedef __attribute__((ext_vector_type(4))) float f32x4;

union BF8U { bf16x8 v; unsigned short s[8]; };

__device__ __forceinline__ unsigned short f2b(float f) {
    union { float f; unsigned u; } v; v.f = f;
    unsigned r = v.u + 0x7fffu + ((v.u >> 16) & 1u);
    return (unsigned short)(r >> 16);
}

__device__ __forceinline__ float b2f(unsigned short u) {
    union { unsigned u; float f; } v; v.u = (unsigned)u << 16; return v.f;
}

__device__ __forceinline__ float fast_tanh(float x) {
    x = fminf(fmaxf(x, -15.f), 15.f);
    const float e = __expf(2.f * x);
    return (e - 1.f) / (e + 1.f);
}

__device__ __forceinline__ void gl2lds16(const void* g, void* l) {
    __builtin_amdgcn_global_load_lds((__attribute__((address_space(1))) void*)(void*)g,
                                     (__attribute__((address_space(3))) void*)l, 16, 0, 0);
}

__device__ __forceinline__ bf16x8 ldsfrag(const unsigned short* p) {
    return *(const bf16x8*)p;
}

__device__ __forceinline__ bf16x8 pack8(float4 a, float4 b) {
    BF8U u;
    u.s[0] = f2b(a.x); u.s[1] = f2b(a.y); u.s[2] = f2b(a.z); u.s[3] = f2b(a.w);
    u.s[4] = f2b(b.x); u.s[5] = f2b(b.y); u.s[6] = f2b(b.z); u.s[7] = f2b(b.w);
    return u.v;
}

// ---------------- merged init: blocks [0,4096) build A; [4096,5120) run encoder ------
__global__ __launch_bounds__(256, 2) void init_k(const float* __restrict__ emb,
                                                 unsigned short* __restrict__ A,
                                                 const float* __restrict__ hist,
                                                 const float* __restrict__ tid_emb,
                                                 const float* __restrict__ diw_emb,
                                                 const float* __restrict__ t2f_w,
                                                 const float* __restrict__ t2f_b,
                                                 const float* __restrict__ enc_w1,
                                                 const float* __restrict__ enc_b1,
                                                 const float* __restrict__ enc_w2,
                                                 const float* __restrict__ enc_b2,
                                                 float* __restrict__ field,
                                                 unsigned short* __restrict__ fT) {
    __shared__ float sc[NNODE];
    __shared__ float red[256];
    const int tid = threadIdx.x;
    if (blockIdx.x < NNODE) {
        // ---- build_A ----
        const int n = blockIdx.x;
        float e[EMBD];
#pragma unroll
        for (int c = 0; c < EMBD; c++) e[c] = emb[(size_t)n * EMBD + c];
        float mx = 0.f;
        for (int m = tid; m < NNODE; m += 256) {
            float s = 0.f;
#pragma unroll
            for (int c = 0; c < EMBD; c++) s += e[c] * emb[(size_t)m * EMBD + c];
            s = fmaxf(s, 0.f);
            sc[m] = s;
            mx = fmaxf(mx, s);
        }
        red[tid] = mx;
        __syncthreads();
        for (int off = 128; off > 0; off >>= 1) {
            if (tid < off) red[tid] = fmaxf(red[tid], red[tid + off]);
            __syncthreads();
        }
        mx = red[0];
        __syncthreads();
        float sum = 0.f;
        for (int m = tid; m < NNODE; m += 256) {
            float v = expf(sc[m] - mx);
            sc[m] = v;
            sum += v;
        }
        red[tid] = sum;
        __syncthreads();
        for (int off = 128; off > 0; off >>= 1) {
            if (tid < off) red[tid] += red[tid + off];
            __syncthreads();
        }
        const float inv = 1.f / red[0];
        for (int m = tid; m < NNODE; m += 256)
            A[(size_t)n * NNODE + m] = f2b(sc[m] * inv);
    } else {
        // ---- encoder ----
        const int gid = (blockIdx.x - NNODE) * 256 + tid;
        const int b = gid >> 12;
        const int n = gid & (NNODE - 1);
        const float* hb = hist + ((size_t)b * LHIST * NNODE + n) * CCH;
        float x[LHIST * CCH];
#pragma unroll
        for (int l = 0; l < LHIST; l++) {
            x[l * 3 + 0] = hb[(size_t)l * NNODE * CCH + 0];
            x[l * 3 + 1] = hb[(size_t)l * NNODE * CCH + 1];
            x[l * 3 + 2] = hb[(size_t)l * NNODE * CCH + 2];
        }
        float f[FD];
#pragma unroll
        for (int o = 0; o < FD; o++) f[o] = enc_b2[o] + t2f_b[o];
        for (int j = 0; j < HD; j++) {
            float h = enc_b1[j];
#pragma unroll
            for (int k = 0; k < LHIST * CCH; k++) h += x[k] * enc_w1[k * HD + j];
            h = fmaxf(h, 0.f);
#pragma unroll
            for (int o = 0; o < FD; o++) f[o] += h * enc_w2[j * FD + o];
        }
        const int ti = min(max((int)(x[11 * 3 + 1] * 288.0f), 0), TIDN - 1);
        const int di = min(max((int)(x[11 * 3 + 2] * 7.0f), 0), DIWN - 1);
        for (int g = 0; g < TDD; g++) {
            const float tg = tid_emb[ti * TDD + g];
            const float dg = diw_emb[di * TDD + g];
#pragma unroll
            for (int o = 0; o < FD; o++)
                f[o] += tg * t2f_w[g * FD + o] + dg * t2f_w[(TDD + g) * FD + o];
        }
#pragma unroll
        for (int o4 = 0; o4 < FD / 4; o4++) {
            float4 v = {f[o4 * 4 + 0], f[o4 * 4 + 1], f[o4 * 4 + 2], f[o4 * 4 + 3]};
            *(float4*)&field[(size_t)gid * FD + o4 * 4] = v;
        }
#pragma unroll
        for (int o = 0; o < FD; o++)
            fT[(size_t)(b * FD + o) * NNODE + n] = f2b(f[o]);
    }
}

// ===================== fused GEMM + step (all 4 steps; last fuses decoder) ===========
// K-loop: async global_load_lds double-buffer, ONE barrier per K-iter. On last step,
// decoder weights are staged into the (K-loop-idle) Hs region and the epilogue runs
// the decoder MLP instead of the field/state/fT stores.
#define TPAD 36
#define QHP  72
#define QFP  40
__global__ __launch_bounds__(256) void gemm_step(const unsigned short* __restrict__ X,
                                                 const unsigned short* __restrict__ Y,
                                                 float* __restrict__ field,
                                                 unsigned short* __restrict__ state,
                                                 unsigned short* __restrict__ fTo,
                                                 const float* __restrict__ pde_w1,
                                                 const float* __restrict__ pde_b1,
                                                 const float* __restrict__ pde_w2,
                                                 const float* __restrict__ pde_b2,
                                                 const float* __restrict__ ss_win,
                                                 const float* __restrict__ ss_wst,
                                                 const float* __restrict__ ss_b,
                                                 const float* __restrict__ ss_wout,
                                                 const float* __restrict__ ss_bout,
                                                 const float* __restrict__ pde_mix,
                                                 const float* __restrict__ dec_w1,
                                                 const float* __restrict__ dec_b1,
                                                 const float* __restrict__ dec_w2,
                                                 const float* __restrict__ dec_b2,
                                                 float* __restrict__ out,
                                                 int first, int last) {
    constexpr int K = KDIM;
    constexpr int BK = 32;
    __shared__ __align__(16) unsigned short SM0[512 * TPAD];   // dbuf (32768B) / T (36864B)
    __shared__ __align__(16) unsigned short W1T[HD * FD];
    __shared__ __align__(16) unsigned short W2T[FD * HD];
    __shared__ __align__(16) unsigned short WinT[FD * FD];
    __shared__ __align__(16) unsigned short WstT[FD * FD];
    __shared__ __align__(16) unsigned short WoutT[FD * FD];
    __shared__ __align__(16) unsigned short Hs[4 * 32 * QHP];  // also dec-weight stage
    __shared__ __align__(16) unsigned short Fs[4 * 32 * QFP];

    const int tid = threadIdx.x;
    const int wave = tid >> 6;
    const int lane = tid & 63;

    // stage step weights (bf16, transposed)
    for (int i = tid; i < HD * FD; i += 256) W1T[(i & 63) * FD + (i >> 6)] = f2b(pde_w1[i]);
    for (int i = tid; i < HD * FD; i += 256) W2T[(i & 31) * HD + (i >> 5)] = f2b(pde_w2[i]);
    for (int i = tid; i < FD * FD; i += 256) {
        WinT [(i & 31) * FD + (i >> 5)] = f2b(ss_win[i]);
        WstT [(i & 31) * FD + (i >> 5)] = f2b(ss_wst[i]);
        WoutT[(i & 31) * FD + (i >> 5)] = f2b(ss_wout[i]);
    }
    if (last) {
        // decoder weights -> Hs overlay (Hs idle until the step phase)
        for (int i = tid; i < HD * FD; i += 256)
            Hs[(i & 63) * FD + (i >> 6)] = f2b(dec_w1[i]);            // Wd1T [j][f]
        for (int i = tid; i < 16 * HD; i += 256) {
            const int o = i >> 6, j = i & 63;
            Hs[HD * FD + i] = (o < OUTD) ? f2b(dec_w2[j * OUTD + o]) : (unsigned short)0;
        }
    }

    // XCD-aware block remap
    const int l = blockIdx.x + 16 * blockIdx.y;   // 0..511
    const int xcd = l & 7;
    const int rem = l >> 3;
    const int by = xcd * 4 + (rem & 3);           // 0..31
    const int bx = rem >> 2;                      // 0..15
    const int i0 = bx * 128;
    const int j0 = by * 128;
    const int b0 = i0 >> 5;                       // base batch (4 per block)

    const int wi = (wave >> 1) * 64;
    const int wj = (wave & 1) * 64;

    const int lrow = lane >> 2;
    const int gcol = ((lane & 3) ^ ((lane >> 3) & 3)) * 8;   // swizzled GLOBAL chunk

    const unsigned short* Xg = X + (size_t)(i0 + wave * 32 + lrow) * K + gcol;
    const unsigned short* Yg = Y + (size_t)(j0 + wave * 32 + lrow) * K + gcol;
    unsigned short* XsB = SM0;           // [2][4096]
    unsigned short* YsB = SM0 + 8192;    // [2][4096]
    unsigned short* Xd0 = XsB + (wave * 32) * BK;
    unsigned short* Xd1 = XsB + (wave * 32 + 16) * BK;
    unsigned short* Yd0 = YsB + (wave * 32) * BK;
    unsigned short* Yd1 = YsB + (wave * 32 + 16) * BK;

    const f32x4 zero = {0.f, 0.f, 0.f, 0.f};
    f32x4 acc[4][4];
#pragma unroll
    for (int a = 0; a < 4; a++)
#pragma unroll
        for (int b = 0; b < 4; b++) acc[a][b] = zero;

    const int fr = lane & 15;
    const int q = lane >> 4;
    const int kq8 = (q ^ ((fr >> 1) & 3)) * 8;    // de-swizzled frag chunk

#define GS_ISSUE(P, KT)                                        \
    gl2lds16(Xg + (KT), Xd0 + (P) * 4096);                     \
    gl2lds16(Xg + (KT) + 16 * K, Xd1 + (P) * 4096);            \
    gl2lds16(Yg + (KT), Yd0 + (P) * 4096);                     \
    gl2lds16(Yg + (KT) + 16 * K, Yd1 + (P) * 4096);

#define GS_COMPUTE(P)                                                                 \
    {                                                                                 \
        bf16x8 fa[4], fb[4];                                                          \
        _Pragma("unroll") for (int t = 0; t < 4; t++)                                 \
            fa[t] = *(const bf16x8*)&XsB[(P) * 4096 + (wi + t * 16 + fr) * BK + kq8]; \
        _Pragma("unroll") for (int t = 0; t < 4; t++)                                 \
            fb[t] = *(const bf16x8*)&YsB[(P) * 4096 + (wj + t * 16 + fr) * BK + kq8]; \
        _Pragma("unroll") for (int mi = 0; mi < 4; mi++)                              \
            _Pragma("unroll") for (int ni = 0; ni < 4; ni++)                          \
                acc[mi][ni] = __builtin_amdgcn_mfma_f32_16x16x32_bf16(                \
                    fa[mi], fb[ni], acc[mi][ni], 0, 0, 0);                            \
    }

    GS_ISSUE(0, 0);
    __syncthreads();   // also covers weight staging
    int p = 0;
    for (int kt = 0; kt < K; kt += BK) {
        if (kt + BK < K) { GS_ISSUE(p ^ 1, kt + BK); }
        GS_COMPUTE(p);
        __syncthreads();   // drains async loads (they overlapped compute)
        p ^= 1;
    }
#undef GS_COMPUTE
#undef GS_ISSUE

    // ---- acc -> T (Ct, bf16): T[(bb*128 + nl)*TPAD + f] ----
    unsigned short* T = SM0;
    const int r0 = q * 4;
#pragma unroll
    for (int mi = 0; mi < 4; mi++) {
#pragma unroll
        for (int ni = 0; ni < 4; ni++) {
            const int R0 = i0 + wi + mi * 16 + r0;
            const int nl = wj + ni * 16 + fr;
            ushort4 pk = {f2b(acc[mi][ni][0]), f2b(acc[mi][ni][1]),
                          f2b(acc[mi][ni][2]), f2b(acc[mi][ni][3])};
            *(ushort4*)&T[((((R0 >> 5) & 3) << 7) + nl) * TPAD + (R0 & 31)] = pk;
        }
    }
    __syncthreads();

    // ---- step math: wave handles rows [wave*128, +128) in 4 quarters of 32 ----
    const int ln = fr;
    const int kq = q * 8;
    unsigned short* Hw = &Hs[wave * 32 * QHP];
    unsigned short* Fw = &Fs[wave * 32 * QFP];
    const float alpha = 1.f / (1.f + __expf(-pde_mix[0]));
    const float dt = 0.25f;

    bf16x8 w1f[4], w2f[2][2], winf[2], wstf[2], woutf[2];
#pragma unroll
    for (int nj = 0; nj < 4; nj++) w1f[nj] = ldsfrag(&W1T[(nj * 16 + ln) * FD + kq]);
#pragma unroll
    for (int nf = 0; nf < 2; nf++) {
#pragma unroll
        for (int kk = 0; kk < 2; kk++)
            w2f[nf][kk] = ldsfrag(&W2T[(nf * 16 + ln) * HD + kk * 32 + kq]);
        winf[nf]  = ldsfrag(&WinT [(nf * 16 + ln) * FD + kq]);
        wstf[nf]  = ldsfrag(&WstT [(nf * 16 + ln) * FD + kq]);
        woutf[nf] = ldsfrag(&WoutT[(nf * 16 + ln) * FD + kq]);
    }
    float b1v[4], b2v[2], bsv[2], bov[2];
#pragma unroll
    for (int nj = 0; nj < 4; nj++) b1v[nj] = pde_b1[nj * 16 + ln];
#pragma unroll
    for (int nf = 0; nf < 2; nf++) {
        b2v[nf] = pde_b2[nf * 16 + ln];
        bsv[nf] = ss_b[nf * 16 + ln];
        bov[nf] = ss_bout[nf * 16 + ln];
    }

    // decoder frags (last only) — read from Hs overlay BEFORE Hw writes, then barrier
    bf16x8 wd1f[4], wd2f[2];
    float db1v[4];
    float db2v = 0.f;
    if (last) {
#pragma unroll
        for (int nj = 0; nj < 4; nj++) wd1f[nj] = ldsfrag(&Hs[(nj * 16 + ln) * FD + kq]);
#pragma unroll
        for (int kk = 0; kk < 2; kk++) wd2f[kk] = ldsfrag(&Hs[HD * FD + ln * HD + kk * 32 + kq]);
#pragma unroll
        for (int nj = 0; nj < 4; nj++) db1v[nj] = dec_b1[nj * 16 + ln];
        db2v = (ln < OUTD) ? dec_b2[ln] : 0.f;
        __syncthreads();   // all waves done reading Hs overlay before Hw writes
    }

    for (int qtr = 0; qtr < 4; qtr++) {
        const int lb = wave * 128 + qtr * 32;     // local row base in T
        const int bb = lb >> 7;
        const int nl0 = lb & 127;
        const int bg = b0 + bb;
        const int mwg = (bg << 12) + j0 + nl0;    // global (b,n) row base (32 rows)

        bf16x8 fA[2], stA[2];
#pragma unroll
        for (int mi = 0; mi < 2; mi++) {
            const float4* fp = (const float4*)&field[(size_t)(mwg + mi * 16 + ln) * FD + kq];
            fA[mi] = pack8(fp[0], fp[1]);
        }
        if (!first) {
#pragma unroll
            for (int mi = 0; mi < 2; mi++)
                stA[mi] = *(const bf16x8*)&state[(size_t)(mwg + mi * 16 + ln) * FD + kq];
        }

        // H = relu(field @ w1 + b1)
        f32x4 hc[2][4];
#pragma unroll
        for (int mi = 0; mi < 2; mi++)
#pragma unroll
            for (int nj = 0; nj < 4; nj++)
                hc[mi][nj] = __builtin_amdgcn_mfma_f32_16x16x32_bf16(fA[mi], w1f[nj], zero, 0, 0, 0);
#pragma unroll
        for (int mi = 0; mi < 2; mi++)
#pragma unroll
            for (int nj = 0; nj < 4; nj++)
#pragma unroll
                for (int r = 0; r < 4; r++)
                    Hw[(mi * 16 + r0 + r) * QHP + nj * 16 + ln] =
                        f2b(fmaxf(hc[mi][nj][r] + b1v[nj], 0.f));

        // field + Ct in C-layout
        float fld[2][2][4], ctv[2][2][4];
#pragma unroll
        for (int mi = 0; mi < 2; mi++)
#pragma unroll
            for (int nf = 0; nf < 2; nf++)
#pragma unroll
                for (int r = 0; r < 4; r++) {
                    const size_t idx = (size_t)(mwg + mi * 16 + r0 + r) * FD + nf * 16 + ln;
                    fld[mi][nf][r] = field[idx];
                    ctv[mi][nf][r] = b2f(T[(lb + mi * 16 + r0 + r) * TPAD + nf * 16 + ln]);
                }

        // N_F = H @ w2 + b2
        bf16x8 hA[2][2];
#pragma unroll
        for (int mi = 0; mi < 2; mi++)
#pragma unroll
            for (int kk = 0; kk < 2; kk++)
                hA[mi][kk] = ldsfrag(&Hw[(mi * 16 + ln) * QHP + kk * 32 + kq]);
        f32x4 nc[2][2];
#pragma unroll
        for (int mi = 0; mi < 2; mi++)
#pragma unroll
            for (int nf = 0; nf < 2; nf++) {
                f32x4 a = __builtin_amdgcn_mfma_f32_16x16x32_bf16(hA[mi][0], w2f[nf][0], zero, 0, 0, 0);
                nc[mi][nf] = __builtin_amdgcn_mfma_f32_16x16x32_bf16(hA[mi][1], w2f[nf][1], a, 0, 0, 0);
            }

        // fe
        float fe[2][2][4];
#pragma unroll
        for (int mi = 0; mi < 2; mi++)
#pragma unroll
            for (int nf = 0; nf < 2; nf++)
#pragma unroll
                for (int r = 0; r < 4; r++) {
                    const float nfv = nc[mi][nf][r] + b2v[nf];
                    const float fv = fld[mi][nf][r];
                    fe[mi][nf][r] = fv + (alpha * (ctv[mi][nf][r] - fv) + (1.f - alpha) * nfv) * dt;
                    Fw[(mi * 16 + r0 + r) * QFP + nf * 16 + ln] = f2b(fe[mi][nf][r]);
                }

        // S = tanh(fe @ win + st @ wst + b)
        bf16x8 feA[2];
#pragma unroll
        for (int mi = 0; mi < 2; mi++) feA[mi] = ldsfrag(&Fw[(mi * 16 + ln) * QFP + kq]);
        f32x4 sc_[2][2];
#pragma unroll
        for (int mi = 0; mi < 2; mi++)
#pragma unroll
            for (int nf = 0; nf < 2; nf++) {
                f32x4 a = __builtin_amdgcn_mfma_f32_16x16x32_bf16(feA[mi], winf[nf], zero, 0, 0, 0);
                if (!first)
                    a = __builtin_amdgcn_mfma_f32_16x16x32_bf16(stA[mi], wstf[nf], a, 0, 0, 0);
                sc_[mi][nf] = a;
            }
        float sval[2][2][4];
#pragma unroll
        for (int mi = 0; mi < 2; mi++)
#pragma unroll
            for (int nf = 0; nf < 2; nf++)
#pragma unroll
                for (int r = 0; r < 4; r++)
                    sval[mi][nf][r] = fast_tanh(sc_[mi][nf][r] + bsv[nf]);
#pragma unroll
        for (int mi = 0; mi < 2; mi++)
#pragma unroll
            for (int nf = 0; nf < 2; nf++)
#pragma unroll
                for (int r = 0; r < 4; r++)
                    Fw[(mi * 16 + r0 + r) * QFP + nf * 16 + ln] = f2b(sval[mi][nf][r]);

        // field_new = fe + S @ wout + bout
        bf16x8 SA[2];
#pragma unroll
        for (int mi = 0; mi < 2; mi++) SA[mi] = ldsfrag(&Fw[(mi * 16 + ln) * QFP + kq]);
        float fnew[2][2][4];
#pragma unroll
        for (int mi = 0; mi < 2; mi++)
#pragma unroll
            for (int nf = 0; nf < 2; nf++) {
                f32x4 oc = __builtin_amdgcn_mfma_f32_16x16x32_bf16(SA[mi], woutf[nf], zero, 0, 0, 0);
#pragma unroll
                for (int r = 0; r < 4; r++)
                    fnew[mi][nf][r] = fe[mi][nf][r] + oc[r] + bov[nf];
            }

        if (!last) {
#pragma unroll
            for (int mi = 0; mi < 2; mi++) {
#pragma unroll
                for (int nf = 0; nf < 2; nf++) {
#pragma unroll
                    for (int r = 0; r < 4; r++) {
                        const size_t idx = (size_t)(mwg + mi * 16 + r0 + r) * FD + nf * 16 + ln;
                        field[idx] = fnew[mi][nf][r];
                        state[idx] = f2b(sval[mi][nf][r]);
                    }
                    ushort4 pk = {f2b(fnew[mi][nf][0]), f2b(fnew[mi][nf][1]),
                                  f2b(fnew[mi][nf][2]), f2b(fnew[mi][nf][3])};
                    const size_t fta = (size_t)(bg * FD + nf * 16 + ln) * NNODE
                                     + j0 + nl0 + mi * 16 + r0;
                    *(ushort4*)&fTo[fta] = pk;
                }
            }
        } else {
            // ---- fused decoder: out[b][o][n] = relu(fnew @ dw1 + db1) @ dw2 + db2 --
#pragma unroll
            for (int mi = 0; mi < 2; mi++)
#pragma unroll
                for (int nf = 0; nf < 2; nf++)
#pragma unroll
                    for (int r = 0; r < 4; r++)
                        Fw[(mi * 16 + r0 + r) * QFP + nf * 16 + ln] = f2b(fnew[mi][nf][r]);
            bf16x8 fnA[2];
#pragma unroll
            for (int mi = 0; mi < 2; mi++) fnA[mi] = ldsfrag(&Fw[(mi * 16 + ln) * QFP + kq]);
            f32x4 h2[2][4];
#pragma unroll
            for (int mi = 0; mi < 2; mi++)
#pragma unroll
                for (int nj = 0; nj < 4; nj++)
                    h2[mi][nj] = __builtin_amdgcn_mfma_f32_16x16x32_bf16(fnA[mi], wd1f[nj], zero, 0, 0, 0);
#pragma unroll
            for (int mi = 0; mi < 2; mi++)
#pragma unroll
                for (int nj = 0; nj < 4; nj++)
#pragma unroll
                    for (int r = 0; r < 4; r++)
                        Hw[(mi * 16 + r0 + r) * QHP + nj * 16 + ln] =
                            f2b(fmaxf(h2[mi][nj][r] + db1v[nj], 0.f));
            bf16x8 h2A[2][2];
#pragma unroll
            for (int mi = 0; mi < 2; mi++)
#pragma unroll
                for (int kk = 0; kk < 2; kk++)
                    h2A[mi][kk] = ldsfrag(&Hw[(mi * 16 + ln) * QHP + kk * 32 + kq]);
#pragma unroll
            for (int mi = 0; mi < 2; mi++) {
                f32x4 a = __builtin_amdgcn_mfma_f32_16x16x32_bf16(h2A[mi][0], wd2f[0], zero, 0, 0, 0);
                a = __builtin_amdgcn_mfma_f32_16x16x32_bf16(h2A[mi][1], wd2f[1], a, 0, 0, 0);
                if (ln < OUTD) {
                    float4 v = {a[0] + db2v, a[1] + db2v, a[2] + db2v, a[3] + db2v};
                    *(float4*)&out[(size_t)(bg * OUTD + ln) * NNODE + j0 + nl0 + mi * 16 + r0] = v;
                }
            }
        }
    }
}

extern "C" void kernel_launch(void* const* d_in, const int* in_sizes, int n_in,
                              void* d_out, int out_size, void* d_ws, size_t ws_size,
                              hipStream_t stream) {
    (void)in_sizes; (void)n_in; (void)out_size; (void)ws_size;
    const float* hist    = (const float*)d_in[0];
    const float* tid_emb = (const float*)d_in[5];
    const float* diw_emb = (const float*)d_in[6];
    const float* t2f_w   = (const float*)d_in[7];
    const float* t2f_b   = (const float*)d_in[8];
    const float* enc_w1  = (const float*)d_in[9];
    const float* enc_b1  = (const float*)d_in[10];
    const float* enc_w2  = (const float*)d_in[11];
    const float* enc_b2  = (const float*)d_in[12];
    const float* node_emb= (const float*)d_in[13];
    const float* pde_w1  = (const float*)d_in[14];
    const float* pde_b1  = (const float*)d_in[15];
    const float* pde_w2  = (const float*)d_in[16];
    const float* pde_b2  = (const float*)d_in[17];
    const float* ss_win  = (const float*)d_in[18];
    const float* ss_wst  = (const float*)d_in[19];
    const float* ss_b    = (const float*)d_in[20];
    const float* ss_wout = (const float*)d_in[21];
    const float* ss_bout = (const float*)d_in[22];
    const float* dec_w1  = (const float*)d_in[23];
    const float* dec_b1  = (const float*)d_in[24];
    const float* dec_w2  = (const float*)d_in[25];
    const float* dec_b2  = (const float*)d_in[26];
    const float* pde_mix = (const float*)d_in[27];

    char* w = (char*)d_ws;
    unsigned short* A_bf = (unsigned short*)w;  w += (size_t)KDIM * KDIM * 2;   // 33.5 MB
    unsigned short* fTa  = (unsigned short*)w;  w += (size_t)MROWS * KDIM * 2;  // 16.8 MB
    unsigned short* fTb  = (unsigned short*)w;  w += (size_t)MROWS * KDIM * 2;  // 16.8 MB
    float* field = (float*)w;                   w += (size_t)MTOT * FD * 4;     // 33.5 MB
    unsigned short* state = (unsigned short*)w; w += (size_t)MTOT * FD * 2;     // 16.8 MB

    // merged build_A + encoder (independent work, one dispatch)
    init_k<<<NNODE + MTOT / 256, 256, 0, stream>>>(node_emb, A_bf, hist, tid_emb,
                                                   diw_emb, t2f_w, t2f_b, enc_w1,
                                                   enc_b1, enc_w2, enc_b2, field, fTa);
    // 4 steps: fused gemm+step; last also fuses the decoder and writes d_out
    unsigned short* fts[5] = {fTa, fTb, fTa, fTb, fTa};
    for (int s = 0; s < 4; s++) {
        gemm_step<<<dim3(16, 32), 256, 0, stream>>>(
            fts[s], A_bf, field, state, fts[s + 1], pde_w1, pde_b1, pde_w2, pde_b2,
            ss_win, ss_wst, ss_b, ss_wout, ss_bout, pde_mix,
            dec_w1, dec_b1, dec_w2, dec_b2, (float*)d_out,
            s == 0 ? 1 : 0, s == 3 ? 1 : 0);
    }
}

// Round 9
// 681.161 us; speedup vs baseline: 1.4432x; 1.4432x over previous
//
#include <hip/hip_runtime.h>

#define BATCH 64
#define LHIST 12
#define NNODE 4096
#define CCH   3
#define FD    32
#define HD    64
#define OUTD  12
#define TIDN  288
#define DIWN  7
#define TDD   16
#define EMBD  10
#define MROWS 2048
#define KDIM  4096
#define MTOT  (BATCH * NNODE)

typedef __attribute__((ext_vector_type(8))) short bf16x8;
typedef __attribute__((ext_vector_type(4))) float f32x4;

union BF8U { bf16x8 v; unsigned short s[8]; };

__device__ __forceinline__ unsigned short f2b(float f) {
    union { float f; unsigned u; } v; v.f = f;
    unsigned r = v.u + 0x7fffu + ((v.u >> 16) & 1u);
    return (unsigned short)(r >> 16);
}

__device__ __forceinline__ float b2f(unsigned short u) {
    union { unsigned u; float f; } v; v.u = (unsigned)u << 16; return v.f;
}

__device__ __forceinline__ float fast_tanh(float x) {
    x = fminf(fmaxf(x, -15.f), 15.f);
    const float e = __expf(2.f * x);
    return (e - 1.f) / (e + 1.f);
}

__device__ __forceinline__ void gl2lds16(const void* g, void* l) {
    __builtin_amdgcn_global_load_lds((__attribute__((address_space(1))) void*)(void*)g,
                                     (__attribute__((address_space(3))) void*)l, 16, 0, 0);
}

__device__ __forceinline__ bf16x8 ldsfrag(const unsigned short* p) {
    return *(const bf16x8*)p;
}

__device__ __forceinline__ bf16x8 pack8(float4 a, float4 b) {
    BF8U u;
    u.s[0] = f2b(a.x); u.s[1] = f2b(a.y); u.s[2] = f2b(a.z); u.s[3] = f2b(a.w);
    u.s[4] = f2b(b.x); u.s[5] = f2b(b.y); u.s[6] = f2b(b.z); u.s[7] = f2b(b.w);
    return u.v;
}

// ---------------- merged init: blocks [0,4096) build A; [4096,5120) run encoder ------
__global__ __launch_bounds__(256, 2) void init_k(const float* __restrict__ emb,
                                                 unsigned short* __restrict__ A,
                                                 const float* __restrict__ hist,
                                                 const float* __restrict__ tid_emb,
                                                 const float* __restrict__ diw_emb,
                                                 const float* __restrict__ t2f_w,
                                                 const float* __restrict__ t2f_b,
                                                 const float* __restrict__ enc_w1,
                                                 const float* __restrict__ enc_b1,
                                                 const float* __restrict__ enc_w2,
                                                 const float* __restrict__ enc_b2,
                                                 float* __restrict__ field,
                                                 unsigned short* __restrict__ fT) {
    __shared__ float sc[NNODE];
    __shared__ float red[256];
    const int tid = threadIdx.x;
    if (blockIdx.x < NNODE) {
        // ---- build_A ----
        const int n = blockIdx.x;
        float e[EMBD];
#pragma unroll
        for (int c = 0; c < EMBD; c++) e[c] = emb[(size_t)n * EMBD + c];
        float mx = 0.f;
        for (int m = tid; m < NNODE; m += 256) {
            float s = 0.f;
#pragma unroll
            for (int c = 0; c < EMBD; c++) s += e[c] * emb[(size_t)m * EMBD + c];
            s = fmaxf(s, 0.f);
            sc[m] = s;
            mx = fmaxf(mx, s);
        }
        red[tid] = mx;
        __syncthreads();
        for (int off = 128; off > 0; off >>= 1) {
            if (tid < off) red[tid] = fmaxf(red[tid], red[tid + off]);
            __syncthreads();
        }
        mx = red[0];
        __syncthreads();
        float sum = 0.f;
        for (int m = tid; m < NNODE; m += 256) {
            float v = expf(sc[m] - mx);
            sc[m] = v;
            sum += v;
        }
        red[tid] = sum;
        __syncthreads();
        for (int off = 128; off > 0; off >>= 1) {
            if (tid < off) red[tid] += red[tid + off];
            __syncthreads();
        }
        const float inv = 1.f / red[0];
        for (int m = tid; m < NNODE; m += 256)
            A[(size_t)n * NNODE + m] = f2b(sc[m] * inv);
    } else {
        // ---- encoder ----
        const int gid = (blockIdx.x - NNODE) * 256 + tid;
        const int b = gid >> 12;
        const int n = gid & (NNODE - 1);
        const float* hb = hist + ((size_t)b * LHIST * NNODE + n) * CCH;
        float x[LHIST * CCH];
#pragma unroll
        for (int l = 0; l < LHIST; l++) {
            x[l * 3 + 0] = hb[(size_t)l * NNODE * CCH + 0];
            x[l * 3 + 1] = hb[(size_t)l * NNODE * CCH + 1];
            x[l * 3 + 2] = hb[(size_t)l * NNODE * CCH + 2];
        }
        float f[FD];
#pragma unroll
        for (int o = 0; o < FD; o++) f[o] = enc_b2[o] + t2f_b[o];
        for (int j = 0; j < HD; j++) {
            float h = enc_b1[j];
#pragma unroll
            for (int k = 0; k < LHIST * CCH; k++) h += x[k] * enc_w1[k * HD + j];
            h = fmaxf(h, 0.f);
#pragma unroll
            for (int o = 0; o < FD; o++) f[o] += h * enc_w2[j * FD + o];
        }
        const int ti = min(max((int)(x[11 * 3 + 1] * 288.0f), 0), TIDN - 1);
        const int di = min(max((int)(x[11 * 3 + 2] * 7.0f), 0), DIWN - 1);
        for (int g = 0; g < TDD; g++) {
            const float tg = tid_emb[ti * TDD + g];
            const float dg = diw_emb[di * TDD + g];
#pragma unroll
            for (int o = 0; o < FD; o++)
                f[o] += tg * t2f_w[g * FD + o] + dg * t2f_w[(TDD + g) * FD + o];
        }
#pragma unroll
        for (int o4 = 0; o4 < FD / 4; o4++) {
            float4 v = {f[o4 * 4 + 0], f[o4 * 4 + 1], f[o4 * 4 + 2], f[o4 * 4 + 3]};
            *(float4*)&field[(size_t)gid * FD + o4 * 4] = v;
        }
#pragma unroll
        for (int o = 0; o < FD; o++)
            fT[(size_t)(b * FD + o) * NNODE + n] = f2b(f[o]);
    }
}

// ===================== fused GEMM + step (steps 0..2 only) ===========================
// K-loop: async global_load_lds double-buffer, ONE barrier per K-iter (R7 = 131 us).
#define TPAD 36
#define QHP  72
#define QFP  40
__global__ __launch_bounds__(256) void gemm_step(const unsigned short* __restrict__ X,
                                                 const unsigned short* __restrict__ Y,
                                                 float* __restrict__ field,
                                                 unsigned short* __restrict__ state,
                                                 unsigned short* __restrict__ fTo,
                                                 const float* __restrict__ pde_w1,
                                                 const float* __restrict__ pde_b1,
                                                 const float* __restrict__ pde_w2,
                                                 const float* __restrict__ pde_b2,
                                                 const float* __restrict__ ss_win,
                                                 const float* __restrict__ ss_wst,
                                                 const float* __restrict__ ss_b,
                                                 const float* __restrict__ ss_wout,
                                                 const float* __restrict__ ss_bout,
                                                 const float* __restrict__ pde_mix,
                                                 int first) {
    constexpr int K = KDIM;
    constexpr int BK = 32;
    __shared__ __align__(16) unsigned short SM0[512 * TPAD];   // dbuf (32768B) / T (36864B)
    __shared__ __align__(16) unsigned short W1T[HD * FD];
    __shared__ __align__(16) unsigned short W2T[FD * HD];
    __shared__ __align__(16) unsigned short WinT[FD * FD];
    __shared__ __align__(16) unsigned short WstT[FD * FD];
    __shared__ __align__(16) unsigned short WoutT[FD * FD];
    __shared__ __align__(16) unsigned short Hs[4 * 32 * QHP];
    __shared__ __align__(16) unsigned short Fs[4 * 32 * QFP];

    const int tid = threadIdx.x;
    const int wave = tid >> 6;
    const int lane = tid & 63;

    for (int i = tid; i < HD * FD; i += 256) W1T[(i & 63) * FD + (i >> 6)] = f2b(pde_w1[i]);
    for (int i = tid; i < HD * FD; i += 256) W2T[(i & 31) * HD + (i >> 5)] = f2b(pde_w2[i]);
    for (int i = tid; i < FD * FD; i += 256) {
        WinT [(i & 31) * FD + (i >> 5)] = f2b(ss_win[i]);
        WstT [(i & 31) * FD + (i >> 5)] = f2b(ss_wst[i]);
        WoutT[(i & 31) * FD + (i >> 5)] = f2b(ss_wout[i]);
    }

    const int l = blockIdx.x + 16 * blockIdx.y;   // 0..511
    const int xcd = l & 7;
    const int rem = l >> 3;
    const int by = xcd * 4 + (rem & 3);           // 0..31
    const int bx = rem >> 2;                      // 0..15
    const int i0 = bx * 128;
    const int j0 = by * 128;
    const int b0 = i0 >> 5;

    const int wi = (wave >> 1) * 64;
    const int wj = (wave & 1) * 64;

    const int lrow = lane >> 2;
    const int gcol = ((lane & 3) ^ ((lane >> 3) & 3)) * 8;   // swizzled GLOBAL chunk

    const unsigned short* Xg = X + (size_t)(i0 + wave * 32 + lrow) * K + gcol;
    const unsigned short* Yg = Y + (size_t)(j0 + wave * 32 + lrow) * K + gcol;
    unsigned short* XsB = SM0;           // [2][4096]
    unsigned short* YsB = SM0 + 8192;    // [2][4096]
    unsigned short* Xd0 = XsB + (wave * 32) * BK;
    unsigned short* Xd1 = XsB + (wave * 32 + 16) * BK;
    unsigned short* Yd0 = YsB + (wave * 32) * BK;
    unsigned short* Yd1 = YsB + (wave * 32 + 16) * BK;

    const f32x4 zero = {0.f, 0.f, 0.f, 0.f};
    f32x4 acc[4][4];
#pragma unroll
    for (int a = 0; a < 4; a++)
#pragma unroll
        for (int b = 0; b < 4; b++) acc[a][b] = zero;

    const int fr = lane & 15;
    const int q = lane >> 4;
    const int kq8 = (q ^ ((fr >> 1) & 3)) * 8;

#define GS_ISSUE(P, KT)                                        \
    gl2lds16(Xg + (KT), Xd0 + (P) * 4096);                     \
    gl2lds16(Xg + (KT) + 16 * K, Xd1 + (P) * 4096);            \
    gl2lds16(Yg + (KT), Yd0 + (P) * 4096);                     \
    gl2lds16(Yg + (KT) + 16 * K, Yd1 + (P) * 4096);

#define GS_COMPUTE(P)                                                                 \
    {                                                                                 \
        bf16x8 fa[4], fb[4];                                                          \
        _Pragma("unroll") for (int t = 0; t < 4; t++)                                 \
            fa[t] = *(const bf16x8*)&XsB[(P) * 4096 + (wi + t * 16 + fr) * BK + kq8]; \
        _Pragma("unroll") for (int t = 0; t < 4; t++)                                 \
            fb[t] = *(const bf16x8*)&YsB[(P) * 4096 + (wj + t * 16 + fr) * BK + kq8]; \
        _Pragma("unroll") for (int mi = 0; mi < 4; mi++)                              \
            _Pragma("unroll") for (int ni = 0; ni < 4; ni++)                          \
                acc[mi][ni] = __builtin_amdgcn_mfma_f32_16x16x32_bf16(                \
                    fa[mi], fb[ni], acc[mi][ni], 0, 0, 0);                            \
    }

    GS_ISSUE(0, 0);
    __syncthreads();
    int p = 0;
    for (int kt = 0; kt < K; kt += BK) {
        if (kt + BK < K) { GS_ISSUE(p ^ 1, kt + BK); }
        GS_COMPUTE(p);
        __syncthreads();
        p ^= 1;
    }
#undef GS_COMPUTE
#undef GS_ISSUE

    // ---- acc -> T (Ct, bf16) ----
    unsigned short* T = SM0;
    const int r0 = q * 4;
#pragma unroll
    for (int mi = 0; mi < 4; mi++) {
#pragma unroll
        for (int ni = 0; ni < 4; ni++) {
            const int R0 = i0 + wi + mi * 16 + r0;
            const int nl = wj + ni * 16 + fr;
            ushort4 pk = {f2b(acc[mi][ni][0]), f2b(acc[mi][ni][1]),
                          f2b(acc[mi][ni][2]), f2b(acc[mi][ni][3])};
            *(ushort4*)&T[((((R0 >> 5) & 3) << 7) + nl) * TPAD + (R0 & 31)] = pk;
        }
    }
    __syncthreads();

    // ---- step math ----
    const int ln = fr;
    const int kq = q * 8;
    unsigned short* Hw = &Hs[wave * 32 * QHP];
    unsigned short* Fw = &Fs[wave * 32 * QFP];
    const float alpha = 1.f / (1.f + __expf(-pde_mix[0]));
    const float dt = 0.25f;

    bf16x8 w1f[4], w2f[2][2], winf[2], wstf[2], woutf[2];
#pragma unroll
    for (int nj = 0; nj < 4; nj++) w1f[nj] = ldsfrag(&W1T[(nj * 16 + ln) * FD + kq]);
#pragma unroll
    for (int nf = 0; nf < 2; nf++) {
#pragma unroll
        for (int kk = 0; kk < 2; kk++)
            w2f[nf][kk] = ldsfrag(&W2T[(nf * 16 + ln) * HD + kk * 32 + kq]);
        winf[nf]  = ldsfrag(&WinT [(nf * 16 + ln) * FD + kq]);
        wstf[nf]  = ldsfrag(&WstT [(nf * 16 + ln) * FD + kq]);
        woutf[nf] = ldsfrag(&WoutT[(nf * 16 + ln) * FD + kq]);
    }
    float b1v[4], b2v[2], bsv[2], bov[2];
#pragma unroll
    for (int nj = 0; nj < 4; nj++) b1v[nj] = pde_b1[nj * 16 + ln];
#pragma unroll
    for (int nf = 0; nf < 2; nf++) {
        b2v[nf] = pde_b2[nf * 16 + ln];
        bsv[nf] = ss_b[nf * 16 + ln];
        bov[nf] = ss_bout[nf * 16 + ln];
    }

    for (int qtr = 0; qtr < 4; qtr++) {
        const int lb = wave * 128 + qtr * 32;
        const int bb = lb >> 7;
        const int nl0 = lb & 127;
        const int bg = b0 + bb;
        const int mwg = (bg << 12) + j0 + nl0;

        bf16x8 fA[2], stA[2];
#pragma unroll
        for (int mi = 0; mi < 2; mi++) {
            const float4* fp = (const float4*)&field[(size_t)(mwg + mi * 16 + ln) * FD + kq];
            fA[mi] = pack8(fp[0], fp[1]);
        }
        if (!first) {
#pragma unroll
            for (int mi = 0; mi < 2; mi++)
                stA[mi] = *(const bf16x8*)&state[(size_t)(mwg + mi * 16 + ln) * FD + kq];
        }

        f32x4 hc[2][4];
#pragma unroll
        for (int mi = 0; mi < 2; mi++)
#pragma unroll
            for (int nj = 0; nj < 4; nj++)
                hc[mi][nj] = __builtin_amdgcn_mfma_f32_16x16x32_bf16(fA[mi], w1f[nj], zero, 0, 0, 0);
#pragma unroll
        for (int mi = 0; mi < 2; mi++)
#pragma unroll
            for (int nj = 0; nj < 4; nj++)
#pragma unroll
                for (int r = 0; r < 4; r++)
                    Hw[(mi * 16 + r0 + r) * QHP + nj * 16 + ln] =
                        f2b(fmaxf(hc[mi][nj][r] + b1v[nj], 0.f));

        float fld[2][2][4], ctv[2][2][4];
#pragma unroll
        for (int mi = 0; mi < 2; mi++)
#pragma unroll
            for (int nf = 0; nf < 2; nf++)
#pragma unroll
                for (int r = 0; r < 4; r++) {
                    const size_t idx = (size_t)(mwg + mi * 16 + r0 + r) * FD + nf * 16 + ln;
                    fld[mi][nf][r] = field[idx];
                    ctv[mi][nf][r] = b2f(T[(lb + mi * 16 + r0 + r) * TPAD + nf * 16 + ln]);
                }

        bf16x8 hA[2][2];
#pragma unroll
        for (int mi = 0; mi < 2; mi++)
#pragma unroll
            for (int kk = 0; kk < 2; kk++)
                hA[mi][kk] = ldsfrag(&Hw[(mi * 16 + ln) * QHP + kk * 32 + kq]);
        f32x4 nc[2][2];
#pragma unroll
        for (int mi = 0; mi < 2; mi++)
#pragma unroll
            for (int nf = 0; nf < 2; nf++) {
                f32x4 a = __builtin_amdgcn_mfma_f32_16x16x32_bf16(hA[mi][0], w2f[nf][0], zero, 0, 0, 0);
                nc[mi][nf] = __builtin_amdgcn_mfma_f32_16x16x32_bf16(hA[mi][1], w2f[nf][1], a, 0, 0, 0);
            }

        float fe[2][2][4];
#pragma unroll
        for (int mi = 0; mi < 2; mi++)
#pragma unroll
            for (int nf = 0; nf < 2; nf++)
#pragma unroll
                for (int r = 0; r < 4; r++) {
                    const float nfv = nc[mi][nf][r] + b2v[nf];
                    const float fv = fld[mi][nf][r];
                    fe[mi][nf][r] = fv + (alpha * (ctv[mi][nf][r] - fv) + (1.f - alpha) * nfv) * dt;
                    Fw[(mi * 16 + r0 + r) * QFP + nf * 16 + ln] = f2b(fe[mi][nf][r]);
                }

        bf16x8 feA[2];
#pragma unroll
        for (int mi = 0; mi < 2; mi++) feA[mi] = ldsfrag(&Fw[(mi * 16 + ln) * QFP + kq]);
        f32x4 sc_[2][2];
#pragma unroll
        for (int mi = 0; mi < 2; mi++)
#pragma unroll
            for (int nf = 0; nf < 2; nf++) {
                f32x4 a = __builtin_amdgcn_mfma_f32_16x16x32_bf16(feA[mi], winf[nf], zero, 0, 0, 0);
                if (!first)
                    a = __builtin_amdgcn_mfma_f32_16x16x32_bf16(stA[mi], wstf[nf], a, 0, 0, 0);
                sc_[mi][nf] = a;
            }
        float sval[2][2][4];
#pragma unroll
        for (int mi = 0; mi < 2; mi++)
#pragma unroll
            for (int nf = 0; nf < 2; nf++)
#pragma unroll
                for (int r = 0; r < 4; r++)
                    sval[mi][nf][r] = fast_tanh(sc_[mi][nf][r] + bsv[nf]);
#pragma unroll
        for (int mi = 0; mi < 2; mi++)
#pragma unroll
            for (int nf = 0; nf < 2; nf++)
#pragma unroll
                for (int r = 0; r < 4; r++)
                    Fw[(mi * 16 + r0 + r) * QFP + nf * 16 + ln] = f2b(sval[mi][nf][r]);

        bf16x8 SA[2];
#pragma unroll
        for (int mi = 0; mi < 2; mi++) SA[mi] = ldsfrag(&Fw[(mi * 16 + ln) * QFP + kq]);
#pragma unroll
        for (int mi = 0; mi < 2; mi++) {
#pragma unroll
            for (int nf = 0; nf < 2; nf++) {
                f32x4 oc = __builtin_amdgcn_mfma_f32_16x16x32_bf16(SA[mi], woutf[nf], zero, 0, 0, 0);
                float fnew[4];
#pragma unroll
                for (int r = 0; r < 4; r++) {
                    fnew[r] = fe[mi][nf][r] + oc[r] + bov[nf];
                    const size_t idx = (size_t)(mwg + mi * 16 + r0 + r) * FD + nf * 16 + ln;
                    field[idx] = fnew[r];
                    state[idx] = f2b(sval[mi][nf][r]);
                }
                ushort4 pk = {f2b(fnew[0]), f2b(fnew[1]), f2b(fnew[2]), f2b(fnew[3])};
                const size_t fta = (size_t)(bg * FD + nf * 16 + ln) * NNODE
                                 + j0 + nl0 + mi * 16 + r0;
                *(ushort4*)&fTo[fta] = pk;
            }
        }
    }
}

// ---------------- split-K GEMM (last step), reg-prefetch distance-2 (R6) -------------
__global__ __launch_bounds__(256) void gemm_bt(const unsigned short* __restrict__ X,
                                               const unsigned short* __restrict__ Y,
                                               unsigned short* __restrict__ Cp) {
    constexpr int K = KDIM;
    constexpr int KS = KDIM / 2;
    constexpr int BK = 32;
    __shared__ __align__(16) unsigned short Xs[2 * 4096];
    __shared__ __align__(16) unsigned short Ys[2 * 4096];
    const int tid = threadIdx.x;
    const int wave = tid >> 6;
    const int lane = tid & 63;

    const int l = blockIdx.x + 16 * blockIdx.y;
    const int xcd = l & 7;
    const int rem = l >> 3;
    const int by = xcd * 4 + (rem & 3);
    const int bx = rem >> 2;
    const int i0 = bx * 128;
    const int j0 = by * 128;
    const int k0 = blockIdx.z * KS;
    unsigned short* C = Cp + (size_t)blockIdx.z * MTOT * FD;

    const int wi = (wave >> 1) * 64;
    const int wj = (wave & 1) * 64;

    const int lrow = lane >> 2;
    const int gcol = (lane & 3) * 8;
    const int scol = ((lane & 3) ^ ((lane >> 3) & 3)) * 8;

    const unsigned short* Xg = X + (size_t)(i0 + wave * 32 + lrow) * K + k0 + gcol;
    const unsigned short* Yg = Y + (size_t)(j0 + wave * 32 + lrow) * K + k0 + gcol;
    const int ld0 = (wave * 32 + lrow) * BK + scol;
    const int ld1 = (wave * 32 + 16 + lrow) * BK + scol;

    const f32x4 zero = {0.f, 0.f, 0.f, 0.f};
    f32x4 acc[4][4];
#pragma unroll
    for (int a = 0; a < 4; a++)
#pragma unroll
        for (int b = 0; b < 4; b++) acc[a][b] = zero;

    const int fr = lane & 15;
    const int q = lane >> 4;
    const int kq8 = (q ^ ((fr >> 1) & 3)) * 8;

#define GB_COMPUTE(P)                                                              \
    {                                                                              \
        bf16x8 fa[4], fb[4];                                                       \
        _Pragma("unroll") for (int t = 0; t < 4; t++)                              \
            fa[t] = *(const bf16x8*)&Xs[(P) * 4096 + (wi + t * 16 + fr) * BK + kq8]; \
        _Pragma("unroll") for (int t = 0; t < 4; t++)                              \
            fb[t] = *(const bf16x8*)&Ys[(P) * 4096 + (wj + t * 16 + fr) * BK + kq8]; \
        _Pragma("unroll") for (int mi = 0; mi < 4; mi++)                           \
            _Pragma("unroll") for (int ni = 0; ni < 4; ni++)                       \
                acc[mi][ni] = __builtin_amdgcn_mfma_f32_16x16x32_bf16(             \
                    fa[mi], fb[ni], acc[mi][ni], 0, 0, 0);                         \
    }

    uint4 ax0 = *(const uint4*)(Xg);
    uint4 ax1 = *(const uint4*)(Xg + 16 * K);
    uint4 ay0 = *(const uint4*)(Yg);
    uint4 ay1 = *(const uint4*)(Yg + 16 * K);
    uint4 bx0 = *(const uint4*)(Xg + BK);
    uint4 bx1 = *(const uint4*)(Xg + BK + 16 * K);
    uint4 by0 = *(const uint4*)(Yg + BK);
    uint4 by1 = *(const uint4*)(Yg + BK + 16 * K);
    *(uint4*)&Xs[ld0] = ax0; *(uint4*)&Xs[ld1] = ax1;
    *(uint4*)&Ys[ld0] = ay0; *(uint4*)&Ys[ld1] = ay1;
    __syncthreads();

    int p = 0;
    for (int kt = 0; kt < KS; kt += 2 * BK) {
        if (kt + 2 * BK < KS) {
            ax0 = *(const uint4*)(Xg + kt + 2 * BK);
            ax1 = *(const uint4*)(Xg + kt + 2 * BK + 16 * K);
            ay0 = *(const uint4*)(Yg + kt + 2 * BK);
            ay1 = *(const uint4*)(Yg + kt + 2 * BK + 16 * K);
        }
        GB_COMPUTE(p);
        {
            const int np = p ^ 1;
            *(uint4*)&Xs[np * 4096 + ld0] = bx0; *(uint4*)&Xs[np * 4096 + ld1] = bx1;
            *(uint4*)&Ys[np * 4096 + ld0] = by0; *(uint4*)&Ys[np * 4096 + ld1] = by1;
            __syncthreads();
        }
        if (kt + 3 * BK < KS) {
            bx0 = *(const uint4*)(Xg + kt + 3 * BK);
            bx1 = *(const uint4*)(Xg + kt + 3 * BK + 16 * K);
            by0 = *(const uint4*)(Yg + kt + 3 * BK);
            by1 = *(const uint4*)(Yg + kt + 3 * BK + 16 * K);
        }
        GB_COMPUTE(p ^ 1);
        if (kt + 2 * BK < KS) {
            *(uint4*)&Xs[p * 4096 + ld0] = ax0; *(uint4*)&Xs[p * 4096 + ld1] = ax1;
            *(uint4*)&Ys[p * 4096 + ld0] = ay0; *(uint4*)&Ys[p * 4096 + ld1] = ay1;
            __syncthreads();
        }
    }
#undef GB_COMPUTE

    const int r0 = q * 4;
#pragma unroll
    for (int mi = 0; mi < 4; mi++) {
#pragma unroll
        for (int ni = 0; ni < 4; ni++) {
            const int R0 = i0 + wi + mi * 16 + r0;
            const int col = j0 + wj + ni * 16 + fr;
            const size_t addr = ((size_t)(R0 >> 5) * NNODE + col) * FD + (R0 & 31);
            ushort4 pk = {f2b(acc[mi][ni][0]), f2b(acc[mi][ni][1]),
                          f2b(acc[mi][ni][2]), f2b(acc[mi][ni][3])};
            *(ushort4*)&C[addr] = pk;
        }
    }
}

// ---------------- last step: MFMA step + fused decoder -------------------------------
#define HPAD 72
#define FPAD 40
__global__ __launch_bounds__(256, 2) void step_mfma(const unsigned short* __restrict__ Ct0,
                                                    const unsigned short* __restrict__ Ct1,
                                                    float* __restrict__ field,
                                                    unsigned short* __restrict__ state,
                                                    const float* __restrict__ pde_w1,
                                                    const float* __restrict__ pde_b1,
                                                    const float* __restrict__ pde_w2,
                                                    const float* __restrict__ pde_b2,
                                                    const float* __restrict__ ss_win,
                                                    const float* __restrict__ ss_wst,
                                                    const float* __restrict__ ss_b,
                                                    const float* __restrict__ ss_wout,
                                                    const float* __restrict__ ss_bout,
                                                    const float* __restrict__ pde_mix,
                                                    const float* __restrict__ dec_w1,
                                                    const float* __restrict__ dec_b1,
                                                    const float* __restrict__ dec_w2,
                                                    const float* __restrict__ dec_b2,
                                                    float* __restrict__ out) {
    __shared__ __align__(16) unsigned short W1T[HD * FD];
    __shared__ __align__(16) unsigned short W2T[FD * HD];
    __shared__ __align__(16) unsigned short WinT[FD * FD];
    __shared__ __align__(16) unsigned short WstT[FD * FD];
    __shared__ __align__(16) unsigned short WoutT[FD * FD];
    __shared__ __align__(16) unsigned short Wd1T[HD * FD];
    __shared__ __align__(16) unsigned short Wd2T[16 * HD];
    __shared__ __align__(16) unsigned short Hs[4 * 64 * HPAD];
    __shared__ __align__(16) unsigned short Fs[4 * 64 * FPAD];

    const int tid = threadIdx.x;
    for (int i = tid; i < HD * FD; i += 256) W1T[(i & 63) * FD + (i >> 6)] = f2b(pde_w1[i]);
    for (int i = tid; i < HD * FD; i += 256) W2T[(i & 31) * HD + (i >> 5)] = f2b(pde_w2[i]);
    for (int i = tid; i < FD * FD; i += 256) {
        WinT [(i & 31) * FD + (i >> 5)] = f2b(ss_win[i]);
        WstT [(i & 31) * FD + (i >> 5)] = f2b(ss_wst[i]);
        WoutT[(i & 31) * FD + (i >> 5)] = f2b(ss_wout[i]);
    }
    for (int i = tid; i < HD * FD; i += 256)
        Wd1T[(i & 63) * FD + (i >> 6)] = f2b(dec_w1[i]);
    for (int i = tid; i < 16 * HD; i += 256) {
        const int o = i >> 6, j = i & 63;
        Wd2T[i] = (o < OUTD) ? f2b(dec_w2[j * OUTD + o]) : (unsigned short)0;
    }
    __syncthreads();

    const int wv = tid >> 6;
    const int lane = tid & 63;
    const int ln = lane & 15;
    const int q = lane >> 4;
    const int kq = q * 8;
    const int r0 = q * 4;
    const int mw = blockIdx.x * 256 + wv * 64;
    const int b = mw >> 12;
    const int n0 = mw & (NNODE - 1);
    unsigned short* Hw = &Hs[wv * 64 * HPAD];
    unsigned short* Fw = &Fs[wv * 64 * FPAD];

    const float alpha = 1.f / (1.f + __expf(-pde_mix[0]));
    const float dt = 0.25f;

    bf16x8 w1f[4], w2f[2][2], winf[2], wstf[2], woutf[2];
#pragma unroll
    for (int nj = 0; nj < 4; nj++) w1f[nj] = ldsfrag(&W1T[(nj * 16 + ln) * FD + kq]);
#pragma unroll
    for (int nf = 0; nf < 2; nf++) {
#pragma unroll
        for (int kk = 0; kk < 2; kk++)
            w2f[nf][kk] = ldsfrag(&W2T[(nf * 16 + ln) * HD + kk * 32 + kq]);
        winf[nf]  = ldsfrag(&WinT [(nf * 16 + ln) * FD + kq]);
        wstf[nf]  = ldsfrag(&WstT [(nf * 16 + ln) * FD + kq]);
        woutf[nf] = ldsfrag(&WoutT[(nf * 16 + ln) * FD + kq]);
    }

    float b1v[4], b2v[2], bsv[2], bov[2];
#pragma unroll
    for (int nj = 0; nj < 4; nj++) b1v[nj] = pde_b1[nj * 16 + ln];
#pragma unroll
    for (int nf = 0; nf < 2; nf++) {
        b2v[nf] = pde_b2[nf * 16 + ln];
        bsv[nf] = ss_b[nf * 16 + ln];
        bov[nf] = ss_bout[nf * 16 + ln];
    }

    bf16x8 fA[4], stA[4];
#pragma unroll
    for (int mi = 0; mi < 4; mi++) {
        const float4* fp = (const float4*)&field[(size_t)(mw + mi * 16 + ln) * FD + kq];
        fA[mi] = pack8(fp[0], fp[1]);
    }
#pragma unroll
    for (int mi = 0; mi < 4; mi++)
        stA[mi] = *(const bf16x8*)&state[(size_t)(mw + mi * 16 + ln) * FD + kq];

    const f32x4 zero = {0.f, 0.f, 0.f, 0.f};

    f32x4 hc[4][4];
#pragma unroll
    for (int mi = 0; mi < 4; mi++)
#pragma unroll
        for (int nj = 0; nj < 4; nj++)
            hc[mi][nj] = __builtin_amdgcn_mfma_f32_16x16x32_bf16(fA[mi], w1f[nj], zero, 0, 0, 0);
#pragma unroll
    for (int mi = 0; mi < 4; mi++)
#pragma unroll
        for (int nj = 0; nj < 4; nj++)
#pragma unroll
            for (int r = 0; r < 4; r++)
                Hw[(mi * 16 + r0 + r) * HPAD + nj * 16 + ln] =
                    f2b(fmaxf(hc[mi][nj][r] + b1v[nj], 0.f));

    float fld[4][2][4], ctv[4][2][4];
#pragma unroll
    for (int mi = 0; mi < 4; mi++)
#pragma unroll
        for (int nf = 0; nf < 2; nf++)
#pragma unroll
            for (int r = 0; r < 4; r++) {
                const size_t idx = (size_t)(mw + mi * 16 + r0 + r) * FD + nf * 16 + ln;
                fld[mi][nf][r] = field[idx];
                ctv[mi][nf][r] = b2f(Ct0[idx]) + b2f(Ct1[idx]);
            }

    bf16x8 hA[4][2];
#pragma unroll
    for (int mi = 0; mi < 4; mi++)
#pragma unroll
        for (int kk = 0; kk < 2; kk++)
            hA[mi][kk] = ldsfrag(&Hw[(mi * 16 + ln) * HPAD + kk * 32 + kq]);
    f32x4 nc[4][2];
#pragma unroll
    for (int mi = 0; mi < 4; mi++)
#pragma unroll
        for (int nf = 0; nf < 2; nf++) {
            f32x4 a = __builtin_amdgcn_mfma_f32_16x16x32_bf16(hA[mi][0], w2f[nf][0], zero, 0, 0, 0);
            nc[mi][nf] = __builtin_amdgcn_mfma_f32_16x16x32_bf16(hA[mi][1], w2f[nf][1], a, 0, 0, 0);
        }

    float fe[4][2][4];
#pragma unroll
    for (int mi = 0; mi < 4; mi++)
#pragma unroll
        for (int nf = 0; nf < 2; nf++)
#pragma unroll
            for (int r = 0; r < 4; r++) {
                const float nfv = nc[mi][nf][r] + b2v[nf];
                const float fv = fld[mi][nf][r];
                fe[mi][nf][r] = fv + (alpha * (ctv[mi][nf][r] - fv) + (1.f - alpha) * nfv) * dt;
                Fw[(mi * 16 + r0 + r) * FPAD + nf * 16 + ln] = f2b(fe[mi][nf][r]);
            }

    bf16x8 feA[4];
#pragma unroll
    for (int mi = 0; mi < 4; mi++) feA[mi] = ldsfrag(&Fw[(mi * 16 + ln) * FPAD + kq]);
    f32x4 sc_[4][2];
#pragma unroll
    for (int mi = 0; mi < 4; mi++)
#pragma unroll
        for (int nf = 0; nf < 2; nf++) {
            f32x4 a = __builtin_amdgcn_mfma_f32_16x16x32_bf16(feA[mi], winf[nf], zero, 0, 0, 0);
            a = __builtin_amdgcn_mfma_f32_16x16x32_bf16(stA[mi], wstf[nf], a, 0, 0, 0);
            sc_[mi][nf] = a;
        }
    float sval[4][2][4];
#pragma unroll
    for (int mi = 0; mi < 4; mi++)
#pragma unroll
        for (int nf = 0; nf < 2; nf++)
#pragma unroll
            for (int r = 0; r < 4; r++)
                sval[mi][nf][r] = fast_tanh(sc_[mi][nf][r] + bsv[nf]);
#pragma unroll
    for (int mi = 0; mi < 4; mi++)
#pragma unroll
        for (int nf = 0; nf < 2; nf++)
#pragma unroll
            for (int r = 0; r < 4; r++)
                Fw[(mi * 16 + r0 + r) * FPAD + nf * 16 + ln] = f2b(sval[mi][nf][r]);

    bf16x8 SA[4];
#pragma unroll
    for (int mi = 0; mi < 4; mi++) SA[mi] = ldsfrag(&Fw[(mi * 16 + ln) * FPAD + kq]);
    float fnew[4][2][4];
#pragma unroll
    for (int mi = 0; mi < 4; mi++)
#pragma unroll
        for (int nf = 0; nf < 2; nf++) {
            f32x4 oc = __builtin_amdgcn_mfma_f32_16x16x32_bf16(SA[mi], woutf[nf], zero, 0, 0, 0);
#pragma unroll
            for (int r = 0; r < 4; r++)
                fnew[mi][nf][r] = fe[mi][nf][r] + oc[r] + bov[nf];
        }

    // fused decoder
    bf16x8 wd1f[4], wd2f[2];
#pragma unroll
    for (int nj = 0; nj < 4; nj++) wd1f[nj] = ldsfrag(&Wd1T[(nj * 16 + ln) * FD + kq]);
#pragma unroll
    for (int kk = 0; kk < 2; kk++) wd2f[kk] = ldsfrag(&Wd2T[ln * HD + kk * 32 + kq]);
    float db1v[4];
#pragma unroll
    for (int nj = 0; nj < 4; nj++) db1v[nj] = dec_b1[nj * 16 + ln];
    const float db2v = (ln < OUTD) ? dec_b2[ln] : 0.f;

#pragma unroll
    for (int mi = 0; mi < 4; mi++)
#pragma unroll
        for (int nf = 0; nf < 2; nf++)
#pragma unroll
            for (int r = 0; r < 4; r++)
                Fw[(mi * 16 + r0 + r) * FPAD + nf * 16 + ln] = f2b(fnew[mi][nf][r]);
    bf16x8 fnA[4];
#pragma unroll
    for (int mi = 0; mi < 4; mi++) fnA[mi] = ldsfrag(&Fw[(mi * 16 + ln) * FPAD + kq]);

    f32x4 h2[4][4];
#pragma unroll
    for (int mi = 0; mi < 4; mi++)
#pragma unroll
        for (int nj = 0; nj < 4; nj++)
            h2[mi][nj] = __builtin_amdgcn_mfma_f32_16x16x32_bf16(fnA[mi], wd1f[nj], zero, 0, 0, 0);
#pragma unroll
    for (int mi = 0; mi < 4; mi++)
#pragma unroll
        for (int nj = 0; nj < 4; nj++)
#pragma unroll
            for (int r = 0; r < 4; r++)
                Hw[(mi * 16 + r0 + r) * HPAD + nj * 16 + ln] =
                    f2b(fmaxf(h2[mi][nj][r] + db1v[nj], 0.f));
    bf16x8 h2A[4][2];
#pragma unroll
    for (int mi = 0; mi < 4; mi++)
#pragma unroll
        for (int kk = 0; kk < 2; kk++)
            h2A[mi][kk] = ldsfrag(&Hw[(mi * 16 + ln) * HPAD + kk * 32 + kq]);
#pragma unroll
    for (int mi = 0; mi < 4; mi++) {
        f32x4 a = __builtin_amdgcn_mfma_f32_16x16x32_bf16(h2A[mi][0], wd2f[0], zero, 0, 0, 0);
        a = __builtin_amdgcn_mfma_f32_16x16x32_bf16(h2A[mi][1], wd2f[1], a, 0, 0, 0);
        if (ln < OUTD) {
            float4 v = {a[0] + db2v, a[1] + db2v, a[2] + db2v, a[3] + db2v};
            *(float4*)&out[(size_t)(b * OUTD + ln) * NNODE + n0 + mi * 16 + r0] = v;
        }
    }
}

extern "C" void kernel_launch(void* const* d_in, const int* in_sizes, int n_in,
                              void* d_out, int out_size, void* d_ws, size_t ws_size,
                              hipStream_t stream) {
    (void)in_sizes; (void)n_in; (void)out_size; (void)ws_size;
    const float* hist    = (const float*)d_in[0];
    const float* tid_emb = (const float*)d_in[5];
    const float* diw_emb = (const float*)d_in[6];
    const float* t2f_w   = (const float*)d_in[7];
    const float* t2f_b   = (const float*)d_in[8];
    const float* enc_w1  = (const float*)d_in[9];
    const float* enc_b1  = (const float*)d_in[10];
    const float* enc_w2  = (const float*)d_in[11];
    const float* enc_b2  = (const float*)d_in[12];
    const float* node_emb= (const float*)d_in[13];
    const float* pde_w1  = (const float*)d_in[14];
    const float* pde_b1  = (const float*)d_in[15];
    const float* pde_w2  = (const float*)d_in[16];
    const float* pde_b2  = (const float*)d_in[17];
    const float* ss_win  = (const float*)d_in[18];
    const float* ss_wst  = (const float*)d_in[19];
    const float* ss_b    = (const float*)d_in[20];
    const float* ss_wout = (const float*)d_in[21];
    const float* ss_bout = (const float*)d_in[22];
    const float* dec_w1  = (const float*)d_in[23];
    const float* dec_b1  = (const float*)d_in[24];
    const float* dec_w2  = (const float*)d_in[25];
    const float* dec_b2  = (const float*)d_in[26];
    const float* pde_mix = (const float*)d_in[27];

    char* w = (char*)d_ws;
    unsigned short* A_bf = (unsigned short*)w;  w += (size_t)KDIM * KDIM * 2;   // 33.5 MB
    unsigned short* fTa  = (unsigned short*)w;  w += (size_t)MROWS * KDIM * 2;  // 16.8 MB
    unsigned short* fTb  = (unsigned short*)w;  w += (size_t)MROWS * KDIM * 2;  // 16.8 MB
    float* field = (float*)w;                   w += (size_t)MTOT * FD * 4;     // 33.5 MB
    unsigned short* state = (unsigned short*)w; w += (size_t)MTOT * FD * 2;     // 16.8 MB
    unsigned short* Cp    = (unsigned short*)w; w += (size_t)2 * MTOT * FD * 2; // 33.5 MB

    // merged build_A + encoder
    init_k<<<NNODE + MTOT / 256, 256, 0, stream>>>(node_emb, A_bf, hist, tid_emb,
                                                   diw_emb, t2f_w, t2f_b, enc_w1,
                                                   enc_b1, enc_w2, enc_b2, field, fTa);
    // steps 0..2: fused gemm+step (async dist-1, lean VGPR)
    unsigned short* fts[4] = {fTa, fTb, fTa, fTb};
    for (int s = 0; s < 3; s++) {
        gemm_step<<<dim3(16, 32), 256, 0, stream>>>(
            fts[s], A_bf, field, state, fts[s + 1], pde_w1, pde_b1, pde_w2, pde_b2,
            ss_win, ss_wst, ss_b, ss_wout, ss_bout, pde_mix, s == 0 ? 1 : 0);
    }
    // step 3: split-K reg-dist-2 gemm + step with fused decoder
    gemm_bt<<<dim3(16, 32, 2), 256, 0, stream>>>(fts[3], A_bf, Cp);
    step_mfma<<<MTOT / 256, 256, 0, stream>>>(
        Cp, Cp + (size_t)MTOT * FD, field, state, pde_w1, pde_b1, pde_w2, pde_b2,
        ss_win, ss_wst, ss_b, ss_wout, ss_bout, pde_mix,
        dec_w1, dec_b1, dec_w2, dec_b2, (float*)d_out);
}

// Round 10
// 667.581 us; speedup vs baseline: 1.4726x; 1.0203x over previous
//
#include <hip/hip_runtime.h>

#define BATCH 64
#define LHIST 12
#define NNODE 4096
#define CCH   3
#define FD    32
#define HD    64
#define OUTD  12
#define TIDN  288
#define DIWN  7
#define TDD   16
#define EMBD  10
#define MROWS 2048
#define KDIM  4096
#define MTOT  (BATCH * NNODE)

typedef __attribute__((ext_vector_type(8))) short bf16x8;
typedef __attribute__((ext_vector_type(4))) float f32x4;

union BF8U { bf16x8 v; unsigned short s[8]; };

__device__ __forceinline__ unsigned short f2b(float f) {
    union { float f; unsigned u; } v; v.f = f;
    unsigned r = v.u + 0x7fffu + ((v.u >> 16) & 1u);
    return (unsigned short)(r >> 16);
}

__device__ __forceinline__ float b2f(unsigned short u) {
    union { unsigned u; float f; } v; v.u = (unsigned)u << 16; return v.f;
}

__device__ __forceinline__ float fast_tanh(float x) {
    x = fminf(fmaxf(x, -15.f), 15.f);
    const float e = __expf(2.f * x);
    return (e - 1.f) / (e + 1.f);
}

__device__ __forceinline__ void gl2lds16(const void* g, void* l) {
    __builtin_amdgcn_global_load_lds((__attribute__((address_space(1))) void*)(void*)g,
                                     (__attribute__((address_space(3))) void*)l, 16, 0, 0);
}

__device__ __forceinline__ bf16x8 ldsfrag(const unsigned short* p) {
    return *(const bf16x8*)p;
}

// 8-byte-aligned frag load (two b64) for TPAD=36 rows
__device__ __forceinline__ bf16x8 ldsfrag8(const unsigned short* p) {
    BF8U u;
    *(ushort4*)&u.s[0] = *(const ushort4*)p;
    *(ushort4*)&u.s[4] = *(const ushort4*)(p + 4);
    return u.v;
}

// ---------------- merged init: blocks [0,4096) build A; [4096,5120) run encoder ------
__global__ __launch_bounds__(256, 2) void init_k(const float* __restrict__ emb,
                                                 unsigned short* __restrict__ A,
                                                 const float* __restrict__ hist,
                                                 const float* __restrict__ tid_emb,
                                                 const float* __restrict__ diw_emb,
                                                 const float* __restrict__ t2f_w,
                                                 const float* __restrict__ t2f_b,
                                                 const float* __restrict__ enc_w1,
                                                 const float* __restrict__ enc_b1,
                                                 const float* __restrict__ enc_w2,
                                                 const float* __restrict__ enc_b2,
                                                 float* __restrict__ field,
                                                 unsigned short* __restrict__ fT) {
    __shared__ float sc[NNODE];
    __shared__ float red[256];
    const int tid = threadIdx.x;
    if (blockIdx.x < NNODE) {
        const int n = blockIdx.x;
        float e[EMBD];
#pragma unroll
        for (int c = 0; c < EMBD; c++) e[c] = emb[(size_t)n * EMBD + c];
        float mx = 0.f;
        for (int m = tid; m < NNODE; m += 256) {
            float s = 0.f;
#pragma unroll
            for (int c = 0; c < EMBD; c++) s += e[c] * emb[(size_t)m * EMBD + c];
            s = fmaxf(s, 0.f);
            sc[m] = s;
            mx = fmaxf(mx, s);
        }
        red[tid] = mx;
        __syncthreads();
        for (int off = 128; off > 0; off >>= 1) {
            if (tid < off) red[tid] = fmaxf(red[tid], red[tid + off]);
            __syncthreads();
        }
        mx = red[0];
        __syncthreads();
        float sum = 0.f;
        for (int m = tid; m < NNODE; m += 256) {
            float v = expf(sc[m] - mx);
            sc[m] = v;
            sum += v;
        }
        red[tid] = sum;
        __syncthreads();
        for (int off = 128; off > 0; off >>= 1) {
            if (tid < off) red[tid] += red[tid + off];
            __syncthreads();
        }
        const float inv = 1.f / red[0];
        for (int m = tid; m < NNODE; m += 256)
            A[(size_t)n * NNODE + m] = f2b(sc[m] * inv);
    } else {
        const int gid = (blockIdx.x - NNODE) * 256 + tid;
        const int b = gid >> 12;
        const int n = gid & (NNODE - 1);
        const float* hb = hist + ((size_t)b * LHIST * NNODE + n) * CCH;
        float x[LHIST * CCH];
#pragma unroll
        for (int l = 0; l < LHIST; l++) {
            x[l * 3 + 0] = hb[(size_t)l * NNODE * CCH + 0];
            x[l * 3 + 1] = hb[(size_t)l * NNODE * CCH + 1];
            x[l * 3 + 2] = hb[(size_t)l * NNODE * CCH + 2];
        }
        float f[FD];
#pragma unroll
        for (int o = 0; o < FD; o++) f[o] = enc_b2[o] + t2f_b[o];
        for (int j = 0; j < HD; j++) {
            float h = enc_b1[j];
#pragma unroll
            for (int k = 0; k < LHIST * CCH; k++) h += x[k] * enc_w1[k * HD + j];
            h = fmaxf(h, 0.f);
#pragma unroll
            for (int o = 0; o < FD; o++) f[o] += h * enc_w2[j * FD + o];
        }
        const int ti = min(max((int)(x[11 * 3 + 1] * 288.0f), 0), TIDN - 1);
        const int di = min(max((int)(x[11 * 3 + 2] * 7.0f), 0), DIWN - 1);
        for (int g = 0; g < TDD; g++) {
            const float tg = tid_emb[ti * TDD + g];
            const float dg = diw_emb[di * TDD + g];
#pragma unroll
            for (int o = 0; o < FD; o++)
                f[o] += tg * t2f_w[g * FD + o] + dg * t2f_w[(TDD + g) * FD + o];
        }
#pragma unroll
        for (int o4 = 0; o4 < FD / 4; o4++) {
            float4 v = {f[o4 * 4 + 0], f[o4 * 4 + 1], f[o4 * 4 + 2], f[o4 * 4 + 3]};
            *(float4*)&field[(size_t)gid * FD + o4 * 4] = v;
        }
#pragma unroll
        for (int o = 0; o < FD; o++)
            fT[(size_t)(b * FD + o) * NNODE + n] = f2b(f[o]);
    }
}

// ======================================================================================
// Shared K-loop + step body via macros (gemm_step and gemm_step_last differ in the tail)
#define TPAD 36
#define QHP  72
#define QFP  40

#define GEMM_PROLOGUE()                                                                \
    constexpr int K = KDIM;                                                            \
    constexpr int BK = 32;                                                             \
    __shared__ __align__(16) unsigned short SM0[512 * TPAD];                           \
    __shared__ __align__(16) unsigned short W1T[HD * FD];                              \
    __shared__ __align__(16) unsigned short W2T[FD * HD];                              \
    __shared__ __align__(16) unsigned short WinT[FD * FD];                             \
    __shared__ __align__(16) unsigned short WstT[FD * FD];                             \
    __shared__ __align__(16) unsigned short WoutT[FD * FD];                            \
    __shared__ __align__(16) unsigned short Hs[4 * 32 * QHP];                          \
    __shared__ __align__(16) unsigned short Fs[4 * 32 * QFP];                          \
    const int tid = threadIdx.x;                                                       \
    const int wave = tid >> 6;                                                         \
    const int lane = tid & 63;                                                         \
    for (int i = tid; i < HD * FD; i += 256) W1T[(i & 63) * FD + (i >> 6)] = f2b(pde_w1[i]); \
    for (int i = tid; i < HD * FD; i += 256) W2T[(i & 31) * HD + (i >> 5)] = f2b(pde_w2[i]); \
    for (int i = tid; i < FD * FD; i += 256) {                                         \
        WinT [(i & 31) * FD + (i >> 5)] = f2b(ss_win[i]);                              \
        WstT [(i & 31) * FD + (i >> 5)] = f2b(ss_wst[i]);                              \
        WoutT[(i & 31) * FD + (i >> 5)] = f2b(ss_wout[i]);                             \
    }                                                                                  \
    const int l = blockIdx.x + 16 * blockIdx.y;                                        \
    const int xcd = l & 7;                                                             \
    const int rem = l >> 3;                                                            \
    const int by = xcd * 4 + (rem & 3);                                                \
    const int bx = rem >> 2;                                                           \
    const int i0 = bx * 128;                                                           \
    const int j0 = by * 128;                                                           \
    const int b0 = i0 >> 5;                                                            \
    const int wi = (wave >> 1) * 64;                                                   \
    const int wj = (wave & 1) * 64;                                                    \
    const int lrow = lane >> 2;                                                        \
    const int gcol = ((lane & 3) ^ ((lane >> 3) & 3)) * 8;                             \
    const unsigned short* Xg = X + (size_t)(i0 + wave * 32 + lrow) * K + gcol;         \
    const unsigned short* Yg = Y + (size_t)(j0 + wave * 32 + lrow) * K + gcol;         \
    unsigned short* XsB = SM0;                                                         \
    unsigned short* YsB = SM0 + 8192;                                                  \
    unsigned short* Xd0 = XsB + (wave * 32) * BK;                                      \
    unsigned short* Xd1 = XsB + (wave * 32 + 16) * BK;                                 \
    unsigned short* Yd0 = YsB + (wave * 32) * BK;                                      \
    unsigned short* Yd1 = YsB + (wave * 32 + 16) * BK;                                 \
    const f32x4 zero = {0.f, 0.f, 0.f, 0.f};                                           \
    f32x4 acc[4][4];                                                                   \
    _Pragma("unroll") for (int a = 0; a < 4; a++)                                      \
        _Pragma("unroll") for (int b = 0; b < 4; b++) acc[a][b] = zero;                \
    const int fr = lane & 15;                                                          \
    const int q = lane >> 4;                                                           \
    const int kq8 = (q ^ ((fr >> 1) & 3)) * 8;

#define GS_ISSUE(P, KT)                                        \
    gl2lds16(Xg + (KT), Xd0 + (P) * 4096);                     \
    gl2lds16(Xg + (KT) + 16 * K, Xd1 + (P) * 4096);            \
    gl2lds16(Yg + (KT), Yd0 + (P) * 4096);                     \
    gl2lds16(Yg + (KT) + 16 * K, Yd1 + (P) * 4096);

#define GS_COMPUTE(P)                                                                 \
    {                                                                                 \
        bf16x8 fa[4], fb[4];                                                          \
        _Pragma("unroll") for (int t = 0; t < 4; t++)                                 \
            fa[t] = *(const bf16x8*)&XsB[(P) * 4096 + (wi + t * 16 + fr) * BK + kq8]; \
        _Pragma("unroll") for (int t = 0; t < 4; t++)                                 \
            fb[t] = *(const bf16x8*)&YsB[(P) * 4096 + (wj + t * 16 + fr) * BK + kq8]; \
        _Pragma("unroll") for (int mi = 0; mi < 4; mi++)                              \
            _Pragma("unroll") for (int ni = 0; ni < 4; ni++)                          \
                acc[mi][ni] = __builtin_amdgcn_mfma_f32_16x16x32_bf16(                \
                    fa[mi], fb[ni], acc[mi][ni], 0, 0, 0);                            \
    }

#define GEMM_KLOOP_AND_T()                                                             \
    GS_ISSUE(0, 0);                                                                    \
    __syncthreads();                                                                   \
    int p = 0;                                                                         \
    for (int kt = 0; kt < K; kt += BK) {                                               \
        if (kt + BK < K) { GS_ISSUE(p ^ 1, kt + BK); }                                 \
        GS_COMPUTE(p);                                                                 \
        __syncthreads();                                                               \
        p ^= 1;                                                                        \
    }                                                                                  \
    unsigned short* T = SM0;                                                           \
    const int r0 = q * 4;                                                              \
    _Pragma("unroll") for (int mi = 0; mi < 4; mi++) {                                 \
        _Pragma("unroll") for (int ni = 0; ni < 4; ni++) {                             \
            const int R0 = i0 + wi + mi * 16 + r0;                                     \
            const int nl = wj + ni * 16 + fr;                                          \
            ushort4 pk = {f2b(acc[mi][ni][0]), f2b(acc[mi][ni][1]),                    \
                          f2b(acc[mi][ni][2]), f2b(acc[mi][ni][3])};                   \
            *(ushort4*)&T[((((R0 >> 5) & 3) << 7) + nl) * TPAD + (R0 & 31)] = pk;      \
        }                                                                              \
    }                                                                                  \
    __syncthreads();

#define STEP_SETUP()                                                                   \
    const int ln = fr;                                                                 \
    const int kq = q * 8;                                                              \
    unsigned short* Hw = &Hs[wave * 32 * QHP];                                         \
    unsigned short* Fw = &Fs[wave * 32 * QFP];                                         \
    const float alpha = 1.f / (1.f + __expf(-pde_mix[0]));                             \
    const float dt = 0.25f;                                                            \
    bf16x8 w1f[4], w2f[2][2], winf[2], wstf[2], woutf[2];                              \
    _Pragma("unroll") for (int nj = 0; nj < 4; nj++)                                   \
        w1f[nj] = ldsfrag(&W1T[(nj * 16 + ln) * FD + kq]);                             \
    _Pragma("unroll") for (int nf = 0; nf < 2; nf++) {                                 \
        _Pragma("unroll") for (int kk = 0; kk < 2; kk++)                               \
            w2f[nf][kk] = ldsfrag(&W2T[(nf * 16 + ln) * HD + kk * 32 + kq]);           \
        winf[nf]  = ldsfrag(&WinT [(nf * 16 + ln) * FD + kq]);                         \
        wstf[nf]  = ldsfrag(&WstT [(nf * 16 + ln) * FD + kq]);                         \
        woutf[nf] = ldsfrag(&WoutT[(nf * 16 + ln) * FD + kq]);                         \
    }                                                                                  \
    float b1v[4], b2v[2], bsv[2], bov[2];                                              \
    _Pragma("unroll") for (int nj = 0; nj < 4; nj++) b1v[nj] = pde_b1[nj * 16 + ln];   \
    _Pragma("unroll") for (int nf = 0; nf < 2; nf++) {                                 \
        b2v[nf] = pde_b2[nf * 16 + ln];                                                \
        bsv[nf] = ss_b[nf * 16 + ln];                                                  \
        bov[nf] = ss_bout[nf * 16 + ln];                                               \
    }

// per-quarter step math up to fnew (field read ONCE in C-layout, A-frag via Fw LDS)
#define STEP_QTR_BODY(FIRSTF)                                                          \
    const int lb = wave * 128 + qtr * 32;                                              \
    const int bb = lb >> 7;                                                            \
    const int nl0 = lb & 127;                                                          \
    const int bg = b0 + bb;                                                            \
    const int mwg = (bg << 12) + j0 + nl0;                                             \
    float fld[2][2][4], ctv[2][2][4];                                                  \
    _Pragma("unroll") for (int mi = 0; mi < 2; mi++)                                   \
        _Pragma("unroll") for (int nf = 0; nf < 2; nf++)                               \
            _Pragma("unroll") for (int r = 0; r < 4; r++) {                            \
                const size_t idx = (size_t)(mwg + mi * 16 + r0 + r) * FD + nf * 16 + ln; \
                fld[mi][nf][r] = field[idx];                                           \
                ctv[mi][nf][r] = b2f(T[(lb + mi * 16 + r0 + r) * TPAD + nf * 16 + ln]); \
            }                                                                          \
    bf16x8 stA[2];                                                                     \
    if (!(FIRSTF)) {                                                                   \
        _Pragma("unroll") for (int mi = 0; mi < 2; mi++)                               \
            stA[mi] = *(const bf16x8*)&state[(size_t)(mwg + mi * 16 + ln) * FD + kq];  \
    }                                                                                  \
    _Pragma("unroll") for (int mi = 0; mi < 2; mi++)                                   \
        _Pragma("unroll") for (int nf = 0; nf < 2; nf++)                               \
            _Pragma("unroll") for (int r = 0; r < 4; r++)                              \
                Fw[(mi * 16 + r0 + r) * QFP + nf * 16 + ln] = f2b(fld[mi][nf][r]);     \
    bf16x8 fA[2];                                                                      \
    _Pragma("unroll") for (int mi = 0; mi < 2; mi++)                                   \
        fA[mi] = ldsfrag(&Fw[(mi * 16 + ln) * QFP + kq]);                              \
    f32x4 hc[2][4];                                                                    \
    _Pragma("unroll") for (int mi = 0; mi < 2; mi++)                                   \
        _Pragma("unroll") for (int nj = 0; nj < 4; nj++)                               \
            hc[mi][nj] = __builtin_amdgcn_mfma_f32_16x16x32_bf16(fA[mi], w1f[nj], zero, 0, 0, 0); \
    _Pragma("unroll") for (int mi = 0; mi < 2; mi++)                                   \
        _Pragma("unroll") for (int nj = 0; nj < 4; nj++)                               \
            _Pragma("unroll") for (int r = 0; r < 4; r++)                              \
                Hw[(mi * 16 + r0 + r) * QHP + nj * 16 + ln] =                          \
                    f2b(fmaxf(hc[mi][nj][r] + b1v[nj], 0.f));                          \
    bf16x8 hA[2][2];                                                                   \
    _Pragma("unroll") for (int mi = 0; mi < 2; mi++)                                   \
        _Pragma("unroll") for (int kk = 0; kk < 2; kk++)                               \
            hA[mi][kk] = ldsfrag(&Hw[(mi * 16 + ln) * QHP + kk * 32 + kq]);            \
    f32x4 nc[2][2];                                                                    \
    _Pragma("unroll") for (int mi = 0; mi < 2; mi++)                                   \
        _Pragma("unroll") for (int nf = 0; nf < 2; nf++) {                             \
            f32x4 a = __builtin_amdgcn_mfma_f32_16x16x32_bf16(hA[mi][0], w2f[nf][0], zero, 0, 0, 0); \
            nc[mi][nf] = __builtin_amdgcn_mfma_f32_16x16x32_bf16(hA[mi][1], w2f[nf][1], a, 0, 0, 0); \
        }                                                                              \
    float fe[2][2][4];                                                                 \
    _Pragma("unroll") for (int mi = 0; mi < 2; mi++)                                   \
        _Pragma("unroll") for (int nf = 0; nf < 2; nf++)                               \
            _Pragma("unroll") for (int r = 0; r < 4; r++) {                            \
                const float nfv = nc[mi][nf][r] + b2v[nf];                             \
                const float fv = fld[mi][nf][r];                                       \
                fe[mi][nf][r] = fv + (alpha * (ctv[mi][nf][r] - fv) + (1.f - alpha) * nfv) * dt; \
                Fw[(mi * 16 + r0 + r) * QFP + nf * 16 + ln] = f2b(fe[mi][nf][r]);      \
            }                                                                          \
    bf16x8 feA[2];                                                                     \
    _Pragma("unroll") for (int mi = 0; mi < 2; mi++)                                   \
        feA[mi] = ldsfrag(&Fw[(mi * 16 + ln) * QFP + kq]);                             \
    f32x4 sc_[2][2];                                                                   \
    _Pragma("unroll") for (int mi = 0; mi < 2; mi++)                                   \
        _Pragma("unroll") for (int nf = 0; nf < 2; nf++) {                             \
            f32x4 a = __builtin_amdgcn_mfma_f32_16x16x32_bf16(feA[mi], winf[nf], zero, 0, 0, 0); \
            if (!(FIRSTF))                                                             \
                a = __builtin_amdgcn_mfma_f32_16x16x32_bf16(stA[mi], wstf[nf], a, 0, 0, 0); \
            sc_[mi][nf] = a;                                                           \
        }                                                                              \
    float sval[2][2][4];                                                               \
    _Pragma("unroll") for (int mi = 0; mi < 2; mi++)                                   \
        _Pragma("unroll") for (int nf = 0; nf < 2; nf++)                               \
            _Pragma("unroll") for (int r = 0; r < 4; r++)                              \
                sval[mi][nf][r] = fast_tanh(sc_[mi][nf][r] + bsv[nf]);                 \
    _Pragma("unroll") for (int mi = 0; mi < 2; mi++)                                   \
        _Pragma("unroll") for (int nf = 0; nf < 2; nf++)                               \
            _Pragma("unroll") for (int r = 0; r < 4; r++)                              \
                Fw[(mi * 16 + r0 + r) * QFP + nf * 16 + ln] = f2b(sval[mi][nf][r]);    \
    bf16x8 SA[2];                                                                      \
    _Pragma("unroll") for (int mi = 0; mi < 2; mi++)                                   \
        SA[mi] = ldsfrag(&Fw[(mi * 16 + ln) * QFP + kq]);                              \
    float fnew[2][2][4];                                                               \
    _Pragma("unroll") for (int mi = 0; mi < 2; mi++)                                   \
        _Pragma("unroll") for (int nf = 0; nf < 2; nf++) {                             \
            f32x4 oc = __builtin_amdgcn_mfma_f32_16x16x32_bf16(SA[mi], woutf[nf], zero, 0, 0, 0); \
            _Pragma("unroll") for (int r = 0; r < 4; r++)                              \
                fnew[mi][nf][r] = fe[mi][nf][r] + oc[r] + bov[nf];                     \
        }

// ---------------- steps 0..2: gemm + step, stores next-step operands -----------------
__global__ __launch_bounds__(256) void gemm_step(const unsigned short* __restrict__ X,
                                                 const unsigned short* __restrict__ Y,
                                                 float* __restrict__ field,
                                                 unsigned short* __restrict__ state,
                                                 unsigned short* __restrict__ fTo,
                                                 const float* __restrict__ pde_w1,
                                                 const float* __restrict__ pde_b1,
                                                 const float* __restrict__ pde_w2,
                                                 const float* __restrict__ pde_b2,
                                                 const float* __restrict__ ss_win,
                                                 const float* __restrict__ ss_wst,
                                                 const float* __restrict__ ss_b,
                                                 const float* __restrict__ ss_wout,
                                                 const float* __restrict__ ss_bout,
                                                 const float* __restrict__ pde_mix,
                                                 int first) {
    GEMM_PROLOGUE();
    GEMM_KLOOP_AND_T();
    STEP_SETUP();
    for (int qtr = 0; qtr < 4; qtr++) {
        STEP_QTR_BODY(first);
#pragma unroll
        for (int mi = 0; mi < 2; mi++) {
#pragma unroll
            for (int nf = 0; nf < 2; nf++) {
#pragma unroll
                for (int r = 0; r < 4; r++) {
                    const size_t idx = (size_t)(mwg + mi * 16 + r0 + r) * FD + nf * 16 + ln;
                    field[idx] = fnew[mi][nf][r];
                    state[idx] = f2b(sval[mi][nf][r]);
                }
                ushort4 pk = {f2b(fnew[mi][nf][0]), f2b(fnew[mi][nf][1]),
                              f2b(fnew[mi][nf][2]), f2b(fnew[mi][nf][3])};
                const size_t fta = (size_t)(bg * FD + nf * 16 + ln) * NNODE
                                 + j0 + nl0 + mi * 16 + r0;
                *(ushort4*)&fTo[fta] = pk;
            }
        }
    }
}

// ---------------- step 3: gemm + step + fused decoder, writes d_out only -------------
__global__ __launch_bounds__(256) void gemm_step_last(const unsigned short* __restrict__ X,
                                                      const unsigned short* __restrict__ Y,
                                                      const float* __restrict__ field,
                                                      const unsigned short* __restrict__ state,
                                                      const float* __restrict__ pde_w1,
                                                      const float* __restrict__ pde_b1,
                                                      const float* __restrict__ pde_w2,
                                                      const float* __restrict__ pde_b2,
                                                      const float* __restrict__ ss_win,
                                                      const float* __restrict__ ss_wst,
                                                      const float* __restrict__ ss_b,
                                                      const float* __restrict__ ss_wout,
                                                      const float* __restrict__ ss_bout,
                                                      const float* __restrict__ pde_mix,
                                                      const float* __restrict__ dec_w1,
                                                      const float* __restrict__ dec_b1,
                                                      const float* __restrict__ dec_w2,
                                                      const float* __restrict__ dec_b2,
                                                      float* __restrict__ out) {
    GEMM_PROLOGUE();
    GEMM_KLOOP_AND_T();
    STEP_SETUP();
    // pass 1: step math; fnew (bf16) goes back into T in place (per-wave rows)
    for (int qtr = 0; qtr < 4; qtr++) {
        STEP_QTR_BODY(0);
        (void)bb;
#pragma unroll
        for (int mi = 0; mi < 2; mi++)
#pragma unroll
            for (int nf = 0; nf < 2; nf++)
#pragma unroll
                for (int r = 0; r < 4; r++)
                    T[(lb + mi * 16 + r0 + r) * TPAD + nf * 16 + ln] =
                        f2b(fnew[mi][nf][r]);
    }
    // stage decoder weights into Fs (dead after pass 1); barriers keep frags un-hoisted
    __syncthreads();
    for (int i = tid; i < HD * FD; i += 256)
        Fs[(i & 63) * FD + (i >> 6)] = f2b(dec_w1[i]);              // [j][f]
    for (int i = tid; i < 16 * HD; i += 256) {
        const int o = i >> 6, j = i & 63;
        Fs[HD * FD + i] = (o < OUTD) ? f2b(dec_w2[j * OUTD + o]) : (unsigned short)0;
    }
    __syncthreads();
    // pass 2: decoder MLP from T
    bf16x8 wd1f[4], wd2f[2];
#pragma unroll
    for (int nj = 0; nj < 4; nj++) wd1f[nj] = ldsfrag(&Fs[(nj * 16 + ln) * FD + kq]);
#pragma unroll
    for (int kk = 0; kk < 2; kk++) wd2f[kk] = ldsfrag(&Fs[HD * FD + ln * HD + kk * 32 + kq]);
    float db1v[4];
#pragma unroll
    for (int nj = 0; nj < 4; nj++) db1v[nj] = dec_b1[nj * 16 + ln];
    const float db2v = (ln < OUTD) ? dec_b2[ln] : 0.f;

    for (int qtr = 0; qtr < 4; qtr++) {
        const int lb = wave * 128 + qtr * 32;
        const int nl0 = lb & 127;
        const int bg = b0 + (lb >> 7);
        bf16x8 fnA[2];
#pragma unroll
        for (int mi = 0; mi < 2; mi++)
            fnA[mi] = ldsfrag8(&T[(lb + mi * 16 + ln) * TPAD + kq]);
        f32x4 h2[2][4];
#pragma unroll
        for (int mi = 0; mi < 2; mi++)
#pragma unroll
            for (int nj = 0; nj < 4; nj++)
                h2[mi][nj] = __builtin_amdgcn_mfma_f32_16x16x32_bf16(fnA[mi], wd1f[nj], zero, 0, 0, 0);
#pragma unroll
        for (int mi = 0; mi < 2; mi++)
#pragma unroll
            for (int nj = 0; nj < 4; nj++)
#pragma unroll
                for (int r = 0; r < 4; r++)
                    Hw[(mi * 16 + r0 + r) * QHP + nj * 16 + ln] =
                        f2b(fmaxf(h2[mi][nj][r] + db1v[nj], 0.f));
        bf16x8 h2A[2][2];
#pragma unroll
        for (int mi = 0; mi < 2; mi++)
#pragma unroll
            for (int kk = 0; kk < 2; kk++)
                h2A[mi][kk] = ldsfrag(&Hw[(mi * 16 + ln) * QHP + kk * 32 + kq]);
#pragma unroll
        for (int mi = 0; mi < 2; mi++) {
            f32x4 a = __builtin_amdgcn_mfma_f32_16x16x32_bf16(h2A[mi][0], wd2f[0], zero, 0, 0, 0);
            a = __builtin_amdgcn_mfma_f32_16x16x32_bf16(h2A[mi][1], wd2f[1], a, 0, 0, 0);
            if (ln < OUTD) {
                float4 v = {a[0] + db2v, a[1] + db2v, a[2] + db2v, a[3] + db2v};
                *(float4*)&out[(size_t)(bg * OUTD + ln) * NNODE + j0 + nl0 + mi * 16 + r0] = v;
            }
        }
    }
}

extern "C" void kernel_launch(void* const* d_in, const int* in_sizes, int n_in,
                              void* d_out, int out_size, void* d_ws, size_t ws_size,
                              hipStream_t stream) {
    (void)in_sizes; (void)n_in; (void)out_size; (void)ws_size;
    const float* hist    = (const float*)d_in[0];
    const float* tid_emb = (const float*)d_in[5];
    const float* diw_emb = (const float*)d_in[6];
    const float* t2f_w   = (const float*)d_in[7];
    const float* t2f_b   = (const float*)d_in[8];
    const float* enc_w1  = (const float*)d_in[9];
    const float* enc_b1  = (const float*)d_in[10];
    const float* enc_w2  = (const float*)d_in[11];
    const float* enc_b2  = (const float*)d_in[12];
    const float* node_emb= (const float*)d_in[13];
    const float* pde_w1  = (const float*)d_in[14];
    const float* pde_b1  = (const float*)d_in[15];
    const float* pde_w2  = (const float*)d_in[16];
    const float* pde_b2  = (const float*)d_in[17];
    const float* ss_win  = (const float*)d_in[18];
    const float* ss_wst  = (const float*)d_in[19];
    const float* ss_b    = (const float*)d_in[20];
    const float* ss_wout = (const float*)d_in[21];
    const float* ss_bout = (const float*)d_in[22];
    const float* dec_w1  = (const float*)d_in[23];
    const float* dec_b1  = (const float*)d_in[24];
    const float* dec_w2  = (const float*)d_in[25];
    const float* dec_b2  = (const float*)d_in[26];
    const float* pde_mix = (const float*)d_in[27];

    char* w = (char*)d_ws;
    unsigned short* A_bf = (unsigned short*)w;  w += (size_t)KDIM * KDIM * 2;   // 33.5 MB
    unsigned short* fTa  = (unsigned short*)w;  w += (size_t)MROWS * KDIM * 2;  // 16.8 MB
    unsigned short* fTb  = (unsigned short*)w;  w += (size_t)MROWS * KDIM * 2;  // 16.8 MB
    float* field = (float*)w;                   w += (size_t)MTOT * FD * 4;     // 33.5 MB
    unsigned short* state = (unsigned short*)w; w += (size_t)MTOT * FD * 2;     // 16.8 MB

    init_k<<<NNODE + MTOT / 256, 256, 0, stream>>>(node_emb, A_bf, hist, tid_emb,
                                                   diw_emb, t2f_w, t2f_b, enc_w1,
                                                   enc_b1, enc_w2, enc_b2, field, fTa);
    unsigned short* fts[4] = {fTa, fTb, fTa, fTb};
    for (int s = 0; s < 3; s++) {
        gemm_step<<<dim3(16, 32), 256, 0, stream>>>(
            fts[s], A_bf, field, state, fts[s + 1], pde_w1, pde_b1, pde_w2, pde_b2,
            ss_win, ss_wst, ss_b, ss_wout, ss_bout, pde_mix, s == 0 ? 1 : 0);
    }
    gemm_step_last<<<dim3(16, 32), 256, 0, stream>>>(
        fts[3], A_bf, field, state, pde_w1, pde_b1, pde_w2, pde_b2,
        ss_win, ss_wst, ss_b, ss_wout, ss_bout, pde_mix,
        dec_w1, dec_b1, dec_w2, dec_b2, (float*)d_out);
}